// Round 1
// baseline (2827.577 us; speedup 1.0000x reference)
//
#include <hip/hip_runtime.h>
#include <cstdint>
#include <cstddef>

typedef unsigned short u16;
typedef __attribute__((ext_vector_type(8))) short short8;
typedef __attribute__((ext_vector_type(4))) float f32x4;

static constexpr int BB = 16, DIN = 240, NN = 2048, TT = 2048;
static constexpr long long Y_SIZE = (long long)BB * DIN * TT;          // 7,864,320 f32
static constexpr float SQRT_HALF_F = 0.70710678118654752440f;
static constexpr int HPAD = 64;                 // zero-pad rows each side of h (max shift 54)
static constexpr int HROWS = NN + 2 * HPAD;     // 2176

#define DEVI __device__ __forceinline__

DEVI u16 f2bf(float f) {
    unsigned u = __builtin_bit_cast(unsigned, f);
    u += 0x7FFFu + ((u >> 16) & 1u);
    return (u16)(u >> 16);
}
DEVI float bf2f(u16 h) {
    unsigned u = ((unsigned)h) << 16;
    return __builtin_bit_cast(float, u);
}

DEVI void gld16(const void* g, const void* l) {
    __builtin_amdgcn_global_load_lds(
        (const __attribute__((address_space(1))) unsigned int*)g,
        (__attribute__((address_space(3))) unsigned int*)l, 16, 0, 0);
}

// ---------------- GEMM: C[row][col] = sum_taps sum_k A[row+shift][k] * B[col][k] ----------------
// A: bf16 activations, row-major, contraction contiguous. B: bf16 "weights", row per output col.
// OUTK: 0=f32 [row][ldc]+col, 1=bf16 same, 2=f32 transposed [col][ldc]+row, 3=bf16 transposed.
struct GemmP {
    const u16* A; long long a_bstride; int lda;
    const u16* Bw; long long b_bstride; long long b_tapstride; int ldb;
    int ntaps; int shift0; int dshift; int Kt;
    void* out; long long o_bstride; int ldc;
    const float* bias; int bias_bstride;
    float scale;
    int store_ncols;
};

template <int OUTK>
__global__ __launch_bounds__(256, 2)
void gemm_kernel(GemmP p) {
    __shared__ u16 As[128 * 64];
    __shared__ u16 Bs[128 * 64];
    const int tid = threadIdx.x;
    const int lane = tid & 63, wv = tid >> 6;
    const int wr = wv >> 1, wc = wv & 1;
    const int bz = blockIdx.z;
    const int n0 = blockIdx.x * 128;
    const int c0 = blockIdx.y * 128;
    const u16* Abase = p.A + (long long)bz * p.a_bstride;
    const u16* Bbase = p.Bw + (long long)bz * p.b_bstride;

    f32x4 acc[4][4];
#pragma unroll
    for (int i = 0; i < 4; ++i)
#pragma unroll
        for (int j = 0; j < 4; ++j) acc[i][j] = (f32x4){0.f, 0.f, 0.f, 0.f};

    const int ksteps = p.Kt >> 6;          // BK = 64
    const int tot = p.ntaps * ksteps;
    const int srow = lane >> 3;            // 0..7 row within 8-row chunk
    const int scol = (lane & 7) * 8;       // element col 0..56
    const int fr = lane & 15;
    const int fk = (lane >> 4) * 8;

    for (int t = 0; t < tot; ++t) {
        const int tap = t / ksteps;
        const int ks = (t - tap * ksteps) << 6;
        const int shift = p.shift0 + tap * p.dshift;
        __syncthreads();
        {
            const u16* asrc = Abase + (long long)(n0 + shift) * p.lda + ks;
#pragma unroll
            for (int c = 0; c < 4; ++c) {
                int chunk = wv * 4 + c;
                int row = chunk * 8 + srow;
                gld16(asrc + (long long)row * p.lda + scol, &As[chunk * 512]);
            }
            const u16* bsrc = Bbase + (long long)tap * p.b_tapstride + (long long)c0 * p.ldb + ks;
#pragma unroll
            for (int c = 0; c < 4; ++c) {
                int chunk = wv * 4 + c;
                int row = chunk * 8 + srow;
                gld16(bsrc + (long long)row * p.ldb + scol, &Bs[chunk * 512]);
            }
        }
        asm volatile("s_waitcnt vmcnt(0)" ::: "memory");
        __syncthreads();
#pragma unroll
        for (int kk = 0; kk < 2; ++kk) {
            short8 af[4], bfr[4];
#pragma unroll
            for (int m = 0; m < 4; ++m) {
                int arow = wr * 64 + m * 16 + fr;
                af[m] = *(const short8*)&As[arow * 64 + kk * 32 + fk];
            }
#pragma unroll
            for (int nn2 = 0; nn2 < 4; ++nn2) {
                int brow = wc * 64 + nn2 * 16 + fr;
                bfr[nn2] = *(const short8*)&Bs[brow * 64 + kk * 32 + fk];
            }
#pragma unroll
            for (int m = 0; m < 4; ++m)
#pragma unroll
                for (int nn2 = 0; nn2 < 4; ++nn2)
                    acc[m][nn2] = __builtin_amdgcn_mfma_f32_16x16x32_bf16(
                        af[m], bfr[nn2], acc[m][nn2], 0, 0, 0);
        }
    }

    const float* bias = p.bias ? p.bias + (long long)bz * p.bias_bstride : nullptr;
#pragma unroll
    for (int m = 0; m < 4; ++m) {
#pragma unroll
        for (int nn2 = 0; nn2 < 4; ++nn2) {
#pragma unroll
            for (int r = 0; r < 4; ++r) {
                int row = n0 + wr * 64 + m * 16 + ((lane >> 4) << 2) + r;
                int col = c0 + wc * 64 + nn2 * 16 + (lane & 15);
                if (col >= p.store_ncols) continue;
                float v = acc[m][nn2][r] * p.scale;
                if (bias) v += bias[col];
                long long off = (OUTK == 0 || OUTK == 1)
                                    ? (long long)row * p.ldc + col
                                    : (long long)col * p.ldc + row;
                long long idx = (long long)bz * p.o_bstride + off;
                if (OUTK == 0 || OUTK == 2) ((float*)p.out)[idx] = v;
                else ((u16*)p.out)[idx] = f2bf(v);
            }
        }
    }
}

// ---------------- elementwise / helper kernels ----------------

__global__ void cvt_glu(const float* src, u16* dst) {
    long long t = (long long)blockIdx.x * blockDim.x + threadIdx.x;
    const long long total = 8LL * 5 * 1024 * 512;
    if (t >= total) return;
    int i = (int)(t % 512); long long r = t / 512;
    int o = (int)(r % 1024); r /= 1024;
    int k = (int)(r % 5); int l = (int)(r / 5);
    dst[t] = f2bf(src[(((long long)l * 1024 + o) * 512 + i) * 5 + k]);
}

__global__ void cvt_pad(const float* src, u16* dst, int Os, int Is, int Od, int Id) {
    long long t = (long long)blockIdx.x * blockDim.x + threadIdx.x;
    if (t >= (long long)Od * Id) return;
    int i = (int)(t % Id); int o = (int)(t / Id);
    float v = (o < Os && i < Is) ? src[(long long)o * Is + i] : 0.f;
    dst[t] = f2bf(v);
}

// src [b][Csrc][Len] f32 -> dst [b][Len][Cdst] bf16 (zero-pad channels)
__global__ void transpose_in(const float* src, u16* dst, int Csrc, int Cdst, int Len) {
    __shared__ float tile[32][33];
    int b = blockIdx.z;
    int n0 = blockIdx.x * 32, c0 = blockIdx.y * 32;
    int tx = threadIdx.x, ty = threadIdx.y;
    int c = c0 + ty, n = n0 + tx;
    float v = 0.f;
    if (c < Csrc) v = src[((long long)b * Csrc + c) * Len + n];
    tile[ty][tx] = v;
    __syncthreads();
    dst[((long long)b * Len + (n0 + ty)) * Cdst + (c0 + tx)] = f2bf(tile[tx][ty]);
}

__global__ void zero_pads(u16* h) {
    long long t = (long long)blockIdx.x * blockDim.x + threadIdx.x;
    const long long total = (long long)BB * 128 * 512;
    if (t >= total) return;
    int c = (int)(t % 512); long long r = t / 512;
    int rr = (int)(r % 128); int b = (int)(r / 128);
    int row = rr < HPAD ? rr : (HROWS - 128 + rr);
    h[((long long)b * HROWS + row) * 512 + c] = 0;
}

__global__ void glu_kernel(const float* g, const u16* hin, u16* hout) {
    long long t = (long long)blockIdx.x * blockDim.x + threadIdx.x;
    const long long total = (long long)BB * NN * 64;
    if (t >= total) return;
    int cg = (int)(t % 64); long long rem = t / 64;
    int n = (int)(rem % NN); int b = (int)(rem / NN);
    int c0 = cg * 8;
    const float* ga = g + ((long long)b * NN + n) * 1024 + c0;
    const float* gb = ga + 512;
    long long hoff = ((long long)b * HROWS + HPAD + n) * 512 + c0;
    short8 hv = *(const short8*)(hin + hoff);
    short8 rv;
#pragma unroll
    for (int j = 0; j < 8; ++j) {
        float a = ga[j];
        float bb = gb[j];
        float sig = 1.f / (1.f + __expf(-bb));
        float h = bf2f((u16)hv[j]);
        rv[j] = (short)f2bf((h + a * sig) * SQRT_HALF_F);
    }
    *(short8*)(hout + hoff) = rv;
}

__global__ void prebias_kernel(const float* ct, const float* wcpre, const float* wpre,
                               const float* bpre, float* qbias) {
    __shared__ float s[240];
    int b = blockIdx.x; int tid = threadIdx.x;
    if (tid < 240) {
        float a = 0.f;
        for (int c = 0; c < 8; ++c) a += ct[b * 8 + c] * wcpre[c * 240 + tid];
        s[tid] = a;
    }
    __syncthreads();
    for (int o = tid; o < 512; o += 256) {
        float a = bpre[o];
        for (int d0 = 0; d0 < 240; ++d0) a += wpre[o * 240 + d0] * s[d0];
        qbias[b * 512 + o] = a;
    }
}

__global__ void postbias_kernel(const float* ct, const float* wcpost, const float* wpost,
                                const float* bpost, float* ybias) {
    __shared__ float s[1024];
    int b = blockIdx.x; int tid = threadIdx.x;
    for (int e = tid; e < 1024; e += 256) {
        float a = 0.f;
        for (int c = 0; c < 8; ++c) a += ct[b * 8 + c] * wcpost[c * 1024 + e];
        s[e] = a;
    }
    __syncthreads();
    if (tid < 240) {
        float a = bpost[tid];
        for (int e = 0; e < 1024; ++e) a += wpost[tid * 1024 + e] * s[e];
        ybias[b * 240 + tid] = a;
    }
}

// pass 1: per (b,t) max & 1/sum over n of S[b][n][t]
__global__ void softmax_ml(const float* S, float* Mv, float* Linv) {
    __shared__ float red[4][64];
    __shared__ float red2[4][64];
    int b = blockIdx.y; int t0 = blockIdx.x * 64;
    int tt = threadIdx.x & 63, gq = threadIdx.x >> 6;
    const float* Sb = S + (long long)b * NN * TT;
    float m = -3.4e38f;
    for (int n = gq; n < NN; n += 4) m = fmaxf(m, Sb[(long long)n * TT + t0 + tt]);
    red[gq][tt] = m;
    __syncthreads();
    m = fmaxf(fmaxf(red[0][tt], red[1][tt]), fmaxf(red[2][tt], red[3][tt]));
    float sum = 0.f;
    for (int n = gq; n < NN; n += 4) sum += __expf(Sb[(long long)n * TT + t0 + tt] - m);
    red2[gq][tt] = sum;
    __syncthreads();
    if (gq == 0) {
        sum = red2[0][tt] + red2[1][tt] + red2[2][tt] + red2[3][tt];
        Mv[(long long)b * TT + t0 + tt] = m;
        Linv[(long long)b * TT + t0 + tt] = 1.f / sum;
    }
}

// pass 2: A = exp(S-m)*linv in place (f32) + transposed bf16 copy AT[b][t][n]
__global__ void softmax_norm(float* S, u16* AT, const float* Mv, const float* Linv) {
    __shared__ float tile[32][33];
    int b = blockIdx.z;
    int n0 = blockIdx.x * 32, t0 = blockIdx.y * 32;
    int tx = threadIdx.x, ty = threadIdx.y;
    float* Sb = S + (long long)b * NN * TT;
    long long off = (long long)(n0 + ty) * TT + t0 + tx;
    float m = Mv[(long long)b * TT + t0 + tx];
    float li = Linv[(long long)b * TT + t0 + tx];
    float a = __expf(Sb[off] - m) * li;
    Sb[off] = a;
    tile[ty][tx] = a;
    __syncthreads();
    AT[((long long)b * TT + (t0 + ty)) * NN + (n0 + tx)] = f2bf(tile[tx][ty]);
}

// ---------------- host orchestration ----------------

extern "C" void kernel_launch(void* const* d_in, const int* in_sizes, int n_in,
                              void* d_out, int out_size, void* d_ws, size_t ws_size,
                              hipStream_t stream) {
    const float* in_s        = (const float*)d_in[0];
    const float* in_t        = (const float*)d_in[1];
    const float* c_t         = (const float*)d_in[2];
    const float* enc_start_w = (const float*)d_in[3];
    const float* enc_start_b = (const float*)d_in[4];
    const float* glu_w       = (const float*)d_in[5];
    const float* glu_b       = (const float*)d_in[6];
    const float* enc_end_w   = (const float*)d_in[7];
    const float* enc_end_b   = (const float*)d_in[8];
    const float* wc_pre      = (const float*)d_in[9];
    const float* w_pre       = (const float*)d_in[10];
    const float* b_pre       = (const float*)d_in[11];
    const float* wc_post     = (const float*)d_in[12];
    const float* w_post      = (const float*)d_in[13];
    const float* b_post      = (const float*)d_in[14];

    // workspace layout
    char* w = (char*)d_ws;
    u16* wglu   = (u16*)w; w += 8LL * 5 * 1024 * 512 * 2;
    u16* wstart = (u16*)w; w += 512LL * 256 * 2;
    u16* wend   = (u16*)w; w += 1024LL * 512 * 2;
    u16* wpre   = (u16*)w; w += 512LL * 256 * 2;
    u16* wpost  = (u16*)w; w += 256LL * 1024 * 2;
    u16* XS     = (u16*)w; w += (long long)BB * NN * 256 * 2;
    u16* XT     = (u16*)w; w += (long long)BB * TT * 256 * 2;
    u16* h0     = (u16*)w; w += (long long)BB * HROWS * 512 * 2;
    u16* h1     = (u16*)w; w += (long long)BB * HROWS * 512 * 2;
    u16* Kb     = (u16*)w; w += (long long)BB * NN * 512 * 2;
    u16* Vb     = (u16*)w; w += (long long)BB * 512 * NN * 2;
    u16* Rc     = (u16*)w; w += (long long)BB * TT * 1024 * 2;
    u16* ATb    = (u16*)w; w += (long long)BB * TT * NN * 2;
    float* qbias = (float*)w; w += 16LL * 512 * 4;
    float* ybias = (float*)w; w += 16LL * 256 * 4;
    float* Mv    = (float*)w; w += 16LL * 2048 * 4;
    float* Li    = (float*)w; w += 16LL * 2048 * 4;
    if ((size_t)(w - (char*)d_ws) > ws_size) return;  // insufficient scratch — bail

    float* yout = (float*)d_out;
    float* Sreg = yout + Y_SIZE;   // scores / final A region (also reused as g scratch)
    float* g    = Sreg;            // f32 [B][N][1024] GLU pre-activation scratch

    // ---- conversions / setup ----
    cvt_glu<<<(8LL * 5 * 1024 * 512 + 255) / 256, 256, 0, stream>>>(glu_w, wglu);
    cvt_pad<<<(512 * 256 + 255) / 256, 256, 0, stream>>>(enc_start_w, wstart, 512, 240, 512, 256);
    cvt_pad<<<(1024 * 512 + 255) / 256, 256, 0, stream>>>(enc_end_w, wend, 1024, 512, 1024, 512);
    cvt_pad<<<(512 * 256 + 255) / 256, 256, 0, stream>>>(w_pre, wpre, 512, 240, 512, 256);
    cvt_pad<<<(256 * 1024 + 255) / 256, 256, 0, stream>>>(w_post, wpost, 240, 1024, 256, 1024);
    transpose_in<<<dim3(NN / 32, 256 / 32, BB), dim3(32, 32), 0, stream>>>(in_s, XS, 240, 256, NN);
    transpose_in<<<dim3(TT / 32, 256 / 32, BB), dim3(32, 32), 0, stream>>>(in_t, XT, 240, 256, TT);
    zero_pads<<<((long long)BB * 128 * 512 + 255) / 256, 256, 0, stream>>>(h0);
    zero_pads<<<((long long)BB * 128 * 512 + 255) / 256, 256, 0, stream>>>(h1);
    prebias_kernel<<<16, 256, 0, stream>>>(c_t, wc_pre, w_pre, b_pre, qbias);
    postbias_kernel<<<16, 256, 0, stream>>>(c_t, wc_post, w_post, b_post, ybias);

    // ---- enc_start: XS[2048][256] x wstart[512][256] -> h0 bf16 [n][512] ----
    {
        GemmP p{}; p.A = XS; p.a_bstride = (long long)NN * 256; p.lda = 256;
        p.Bw = wstart; p.b_bstride = 0; p.b_tapstride = 0; p.ldb = 256;
        p.ntaps = 1; p.shift0 = 0; p.dshift = 0; p.Kt = 256;
        p.out = h0 + HPAD * 512; p.o_bstride = (long long)HROWS * 512; p.ldc = 512;
        p.bias = enc_start_b; p.bias_bstride = 0; p.scale = 1.f; p.store_ncols = 512;
        gemm_kernel<1><<<dim3(16, 4, 16), 256, 0, stream>>>(p);
    }

    // ---- 8 GLU blocks ----
    const int dils[8] = {1, 3, 9, 27, 1, 3, 9, 27};
    u16* hin = h0; u16* hout = h1;
    for (int l = 0; l < 8; ++l) {
        GemmP q{}; q.A = hin + HPAD * 512; q.a_bstride = (long long)HROWS * 512; q.lda = 512;
        q.Bw = wglu + (long long)l * 5 * 1024 * 512; q.b_bstride = 0;
        q.b_tapstride = 1024LL * 512; q.ldb = 512;
        q.ntaps = 5; q.shift0 = -2 * dils[l]; q.dshift = dils[l]; q.Kt = 512;
        q.out = g; q.o_bstride = (long long)NN * 1024; q.ldc = 1024;
        q.bias = glu_b + l * 1024; q.bias_bstride = 0; q.scale = 1.f; q.store_ncols = 1024;
        gemm_kernel<0><<<dim3(16, 8, 16), 256, 0, stream>>>(q);
        glu_kernel<<<((long long)BB * NN * 64 + 255) / 256, 256, 0, stream>>>(g, hin, hout);
        u16* tmp = hin; hin = hout; hout = tmp;
    }

    // ---- enc_end: K half (bf16 [n][512]) and V half (bf16 transposed [512][n]) ----
    {
        GemmP p{}; p.A = hin + HPAD * 512; p.a_bstride = (long long)HROWS * 512; p.lda = 512;
        p.Bw = wend; p.b_bstride = 0; p.b_tapstride = 0; p.ldb = 512;
        p.ntaps = 1; p.shift0 = 0; p.dshift = 0; p.Kt = 512;
        p.out = Kb; p.o_bstride = (long long)NN * 512; p.ldc = 512;
        p.bias = enc_end_b; p.bias_bstride = 0; p.scale = 1.f; p.store_ncols = 512;
        gemm_kernel<1><<<dim3(16, 4, 16), 256, 0, stream>>>(p);
        GemmP v = p;
        v.Bw = wend + 512LL * 512; v.bias = enc_end_b + 512;
        v.out = Vb; v.o_bstride = 512LL * NN; v.ldc = NN;
        gemm_kernel<3><<<dim3(16, 4, 16), 256, 0, stream>>>(v);
    }

    // ---- pre-decoder: Q into Rc columns 512..1023 ----
    {
        GemmP p{}; p.A = XT; p.a_bstride = (long long)TT * 256; p.lda = 256;
        p.Bw = wpre; p.b_bstride = 0; p.b_tapstride = 0; p.ldb = 256;
        p.ntaps = 1; p.shift0 = 0; p.dshift = 0; p.Kt = 256;
        p.out = Rc + 512; p.o_bstride = (long long)TT * 1024; p.ldc = 1024;
        p.bias = qbias; p.bias_bstride = 512; p.scale = 1.f; p.store_ncols = 512;
        gemm_kernel<1><<<dim3(16, 4, 16), 256, 0, stream>>>(p);
    }

    // ---- scores: Kb[n][512] x Q(Rc+512)[t][512(of 1024)] -> S f32 [n][t], scaled ----
    {
        GemmP p{}; p.A = Kb; p.a_bstride = (long long)NN * 512; p.lda = 512;
        p.Bw = Rc + 512; p.b_bstride = (long long)TT * 1024; p.b_tapstride = 0; p.ldb = 1024;
        p.ntaps = 1; p.shift0 = 0; p.dshift = 0; p.Kt = 512;
        p.out = Sreg; p.o_bstride = (long long)NN * TT; p.ldc = TT;
        p.bias = nullptr; p.bias_bstride = 0; p.scale = 0.04419417382415922f; // 1/sqrt(512)
        p.store_ncols = TT;
        gemm_kernel<0><<<dim3(16, 16, 16), 256, 0, stream>>>(p);
    }

    // ---- softmax over n (axis=1) + transposed bf16 copy ----
    softmax_ml<<<dim3(TT / 64, BB), 256, 0, stream>>>(Sreg, Mv, Li);
    softmax_norm<<<dim3(NN / 32, TT / 32, BB), dim3(32, 32), 0, stream>>>(Sreg, ATb, Mv, Li);

    // ---- R = V x A  (computed as C[t][d] = sum_n AT[t][n] * V[d][n]) into Rc cols 0..511 ----
    {
        GemmP p{}; p.A = ATb; p.a_bstride = (long long)TT * NN; p.lda = NN;
        p.Bw = Vb; p.b_bstride = 512LL * NN; p.b_tapstride = 0; p.ldb = NN;
        p.ntaps = 1; p.shift0 = 0; p.dshift = 0; p.Kt = NN;
        p.out = Rc; p.o_bstride = (long long)TT * 1024; p.ldc = 1024;
        p.bias = nullptr; p.bias_bstride = 0; p.scale = 1.f; p.store_ncols = 512;
        gemm_kernel<1><<<dim3(16, 4, 16), 256, 0, stream>>>(p);
    }

    // ---- post-decoder: Rc[t][1024] x wpost[256pad][1024] -> y f32 [b][240][t] (transposed store) ----
    {
        GemmP p{}; p.A = Rc; p.a_bstride = (long long)TT * 1024; p.lda = 1024;
        p.Bw = wpost; p.b_bstride = 0; p.b_tapstride = 0; p.ldb = 1024;
        p.ntaps = 1; p.shift0 = 0; p.dshift = 0; p.Kt = 1024;
        p.out = yout; p.o_bstride = (long long)DIN * TT; p.ldc = TT;
        p.bias = ybias; p.bias_bstride = 240; p.scale = 1.f; p.store_ncols = 240;
        gemm_kernel<2><<<dim3(16, 2, 16), 256, 0, stream>>>(p);
    }
}

// Round 2
// 2166.856 us; speedup vs baseline: 1.3049x; 1.3049x over previous
//
#include <hip/hip_runtime.h>
#include <cstdint>
#include <cstddef>

typedef unsigned short u16;
typedef __attribute__((ext_vector_type(8))) short short8;
typedef __attribute__((ext_vector_type(4))) float f32x4;

static constexpr int BB = 16, DIN = 240, NN = 2048, TT = 2048;
static constexpr long long Y_SIZE = (long long)BB * DIN * TT;          // 7,864,320 f32
static constexpr float SQRT_HALF_F = 0.70710678118654752440f;
static constexpr int HPAD = 64;                 // zero-pad rows each side of h (max shift 54)
static constexpr int HROWS = NN + 2 * HPAD;     // 2176

#define DEVI __device__ __forceinline__

DEVI u16 f2bf(float f) {
    unsigned u = __builtin_bit_cast(unsigned, f);
    u += 0x7FFFu + ((u >> 16) & 1u);
    return (u16)(u >> 16);
}
DEVI float bf2f(u16 h) {
    unsigned u = ((unsigned)h) << 16;
    return __builtin_bit_cast(float, u);
}

DEVI void gld16(const void* g, const void* l) {
    __builtin_amdgcn_global_load_lds(
        (const __attribute__((address_space(1))) unsigned int*)g,
        (__attribute__((address_space(3))) unsigned int*)l, 16, 0, 0);
}

// GLU column permutation: GEMM col g -> source output channel o of the conv.
// Chosen so that within each wave's 64-col span, fragments nn2={0,2} hold "a"
// channels and nn2={1,3} hold the matching "b" (gate) channels at +16 cols.
DEVI int glu_perm(int g) {
    int blk = g >> 7, rr = g & 127, wcq = (rr >> 6) & 1, r2 = rr & 63;
    int nn2 = r2 >> 4, fr = r2 & 15;
    int chan = blk * 64 + wcq * 32 + (nn2 >> 1) * 16 + fr;
    return chan + (nn2 & 1) * 512;
}

// ---------------- GEMM: C[row][col] = sum_taps sum_k A[row+shift][k] * B[col][k] ----------------
// OUTK: 0=f32 [row][ldc]+col, 1=bf16 same, 2=f32 transposed, 3=bf16 transposed,
//       4=GLU epilogue: h_out = (h_in + a*sigmoid(b))*sqrt(1/2), bf16 store.
struct GemmP {
    const u16* A; long long a_bstride; int lda;
    const u16* Bw; long long b_bstride; long long b_tapstride; int ldb;
    int ntaps; int shift0; int dshift; int Kt;
    void* out; long long o_bstride; int ldc;
    const float* bias; int bias_bstride;
    float scale;
    int store_ncols;
};

template <int OUTK>
__global__ __launch_bounds__(256, 2)
void gemm_kernel(GemmP p) {
    __shared__ u16 As[128 * 64];
    __shared__ u16 Bs[128 * 64];
    const int tid = threadIdx.x;
    const int lane = tid & 63, wv = tid >> 6;
    const int wr = wv >> 1, wc = wv & 1;
    const int bz = blockIdx.z;
    const int n0 = blockIdx.x * 128;
    const int c0 = blockIdx.y * 128;
    const u16* Abase = p.A + (long long)bz * p.a_bstride;
    const u16* Bbase = p.Bw + (long long)bz * p.b_bstride;

    f32x4 acc[4][4];
#pragma unroll
    for (int i = 0; i < 4; ++i)
#pragma unroll
        for (int j = 0; j < 4; ++j) acc[i][j] = (f32x4){0.f, 0.f, 0.f, 0.f};

    const int ksteps = p.Kt >> 6;          // BK = 64
    const int tot = p.ntaps * ksteps;
    const int srow = lane >> 3;            // 0..7 row within 8-row chunk
    const int scol = (lane & 7) * 8;       // element col 0..56
    const int fr = lane & 15;
    const int fk = (lane >> 4) * 8;

    for (int t = 0; t < tot; ++t) {
        const int tap = t / ksteps;
        const int ks = (t - tap * ksteps) << 6;
        const int shift = p.shift0 + tap * p.dshift;
        __syncthreads();
        {
            const u16* asrc = Abase + (long long)(n0 + shift) * p.lda + ks;
#pragma unroll
            for (int c = 0; c < 4; ++c) {
                int chunk = wv * 4 + c;
                int row = chunk * 8 + srow;
                gld16(asrc + (long long)row * p.lda + scol, &As[chunk * 512]);
            }
            const u16* bsrc = Bbase + (long long)tap * p.b_tapstride + (long long)c0 * p.ldb + ks;
#pragma unroll
            for (int c = 0; c < 4; ++c) {
                int chunk = wv * 4 + c;
                int row = chunk * 8 + srow;
                gld16(bsrc + (long long)row * p.ldb + scol, &Bs[chunk * 512]);
            }
        }
        asm volatile("s_waitcnt vmcnt(0)" ::: "memory");
        __syncthreads();
#pragma unroll
        for (int kk = 0; kk < 2; ++kk) {
            short8 af[4], bfr[4];
#pragma unroll
            for (int m = 0; m < 4; ++m) {
                int arow = wr * 64 + m * 16 + fr;
                af[m] = *(const short8*)&As[arow * 64 + kk * 32 + fk];
            }
#pragma unroll
            for (int nn2 = 0; nn2 < 4; ++nn2) {
                int brow = wc * 64 + nn2 * 16 + fr;
                bfr[nn2] = *(const short8*)&Bs[brow * 64 + kk * 32 + fk];
            }
#pragma unroll
            for (int m = 0; m < 4; ++m)
#pragma unroll
                for (int nn2 = 0; nn2 < 4; ++nn2)
                    acc[m][nn2] = __builtin_amdgcn_mfma_f32_16x16x32_bf16(
                        af[m], bfr[nn2], acc[m][nn2], 0, 0, 0);
        }
    }

    if constexpr (OUTK == 4) {
        // GLU fused epilogue. p.bias = permuted bias (1024), p.out = hout(+HPAD),
        // residual h_in read via Abase (A operand IS h_in) at [row][chan].
        const float* bp = p.bias;
#pragma unroll
        for (int m = 0; m < 4; ++m) {
#pragma unroll
            for (int pr = 0; pr < 2; ++pr) {
                int ca = c0 + wc * 64 + (2 * pr) * 16 + (lane & 15);
                int chan = (c0 >> 1) + wc * 32 + pr * 16 + (lane & 15);
                float biasa = bp[ca], biasb = bp[ca + 16];
#pragma unroll
                for (int r = 0; r < 4; ++r) {
                    int row = n0 + wr * 64 + m * 16 + ((lane >> 4) << 2) + r;
                    float a = acc[m][2 * pr][r] + biasa;
                    float bq = acc[m][2 * pr + 1][r] + biasb;
                    float sig = 1.f / (1.f + __expf(-bq));
                    float h = bf2f(Abase[(long long)row * p.lda + chan]);
                    ((u16*)p.out)[(long long)bz * p.o_bstride + (long long)row * p.ldc + chan]
                        = f2bf((h + a * sig) * SQRT_HALF_F);
                }
            }
        }
        return;
    }

    const float* bias = p.bias ? p.bias + (long long)bz * p.bias_bstride : nullptr;
#pragma unroll
    for (int m = 0; m < 4; ++m) {
#pragma unroll
        for (int nn2 = 0; nn2 < 4; ++nn2) {
#pragma unroll
            for (int r = 0; r < 4; ++r) {
                int row = n0 + wr * 64 + m * 16 + ((lane >> 4) << 2) + r;
                int col = c0 + wc * 64 + nn2 * 16 + (lane & 15);
                if (col >= p.store_ncols) continue;
                float v = acc[m][nn2][r] * p.scale;
                if (bias) v += bias[col];
                long long off = (OUTK == 0 || OUTK == 1)
                                    ? (long long)row * p.ldc + col
                                    : (long long)col * p.ldc + row;
                long long idx = (long long)bz * p.o_bstride + off;
                if (OUTK == 0 || OUTK == 2) ((float*)p.out)[idx] = v;
                else ((u16*)p.out)[idx] = f2bf(v);
            }
        }
    }
}

// ---------------- elementwise / helper kernels ----------------

__global__ void cvt_glu(const float* src, u16* dst) {
    long long t = (long long)blockIdx.x * blockDim.x + threadIdx.x;
    const long long total = 8LL * 5 * 1024 * 512;
    if (t >= total) return;
    int i = (int)(t % 512); long long r = t / 512;
    int g = (int)(r % 1024); r /= 1024;
    int k = (int)(r % 5); int l = (int)(r / 5);
    int o = glu_perm(g);
    dst[t] = f2bf(src[(((long long)l * 1024 + o) * 512 + i) * 5 + k]);
}

__global__ void perm_bias(const float* gb, float* biasP) {
    int t = blockIdx.x * 256 + threadIdx.x;
    if (t >= 8 * 1024) return;
    int g = t & 1023, l = t >> 10;
    biasP[t] = gb[l * 1024 + glu_perm(g)];
}

__global__ void cvt_pad(const float* src, u16* dst, int Os, int Is, int Od, int Id) {
    long long t = (long long)blockIdx.x * blockDim.x + threadIdx.x;
    if (t >= (long long)Od * Id) return;
    int i = (int)(t % Id); int o = (int)(t / Id);
    float v = (o < Os && i < Is) ? src[(long long)o * Is + i] : 0.f;
    dst[t] = f2bf(v);
}

// src [b][Csrc][Len] f32 -> dst [b][Len][Cdst] bf16 (zero-pad channels)
__global__ void transpose_in(const float* src, u16* dst, int Csrc, int Cdst, int Len) {
    __shared__ float tile[32][33];
    int b = blockIdx.z;
    int n0 = blockIdx.x * 32, c0 = blockIdx.y * 32;
    int tx = threadIdx.x, ty = threadIdx.y;
    int c = c0 + ty, n = n0 + tx;
    float v = 0.f;
    if (c < Csrc) v = src[((long long)b * Csrc + c) * Len + n];
    tile[ty][tx] = v;
    __syncthreads();
    dst[((long long)b * Len + (n0 + ty)) * Cdst + (c0 + tx)] = f2bf(tile[tx][ty]);
}

__global__ void zero_pads(u16* h) {
    long long t = (long long)blockIdx.x * blockDim.x + threadIdx.x;
    const long long total = (long long)BB * 128 * 512;
    if (t >= total) return;
    int c = (int)(t % 512); long long r = t / 512;
    int rr = (int)(r % 128); int b = (int)(r / 128);
    int row = rr < HPAD ? rr : (HROWS - 128 + rr);
    h[((long long)b * HROWS + row) * 512 + c] = 0;
}

__global__ void prebias_kernel(const float* ct, const float* wcpre, const float* wpre,
                               const float* bpre, float* qbias) {
    __shared__ float s[240];
    int b = blockIdx.x; int tid = threadIdx.x;
    if (tid < 240) {
        float a = 0.f;
        for (int c = 0; c < 8; ++c) a += ct[b * 8 + c] * wcpre[c * 240 + tid];
        s[tid] = a;
    }
    __syncthreads();
    for (int o = tid; o < 512; o += 256) {
        float a = bpre[o];
        for (int d0 = 0; d0 < 240; ++d0) a += wpre[o * 240 + d0] * s[d0];
        qbias[b * 512 + o] = a;
    }
}

__global__ void postbias_kernel(const float* ct, const float* wcpost, const float* wpost,
                                const float* bpost, float* ybias) {
    __shared__ float s[1024];
    int b = blockIdx.x; int tid = threadIdx.x;
    for (int e = tid; e < 1024; e += 256) {
        float a = 0.f;
        for (int c = 0; c < 8; ++c) a += ct[b * 8 + c] * wcpost[c * 1024 + e];
        s[e] = a;
    }
    __syncthreads();
    if (tid < 240) {
        float a = bpost[tid];
        for (int e = 0; e < 1024; ++e) a += wpost[tid * 1024 + e] * s[e];
        ybias[b * 240 + tid] = a;
    }
}

// One wave per (b,t): read St row (2048 f32) once, reduce max/sum, write AT bf16 + m,1/l.
__global__ __launch_bounds__(256)
void softmax_rows(const float* St, u16* AT, float* Mv, float* Li) {
    int b = blockIdx.y;
    int t = blockIdx.x * 4 + (threadIdx.x >> 6);
    int lane = threadIdx.x & 63;
    const float* row = St + ((long long)b * TT + t) * NN;
    f32x4 v[8];
#pragma unroll
    for (int i = 0; i < 8; ++i) v[i] = ((const f32x4*)row)[i * 64 + lane];
    float m = -3.4e38f;
#pragma unroll
    for (int i = 0; i < 8; ++i)
        m = fmaxf(m, fmaxf(fmaxf(v[i][0], v[i][1]), fmaxf(v[i][2], v[i][3])));
#pragma unroll
    for (int s = 1; s < 64; s <<= 1) m = fmaxf(m, __shfl_xor(m, s, 64));
    float sum = 0.f;
    f32x4 e[8];
#pragma unroll
    for (int i = 0; i < 8; ++i) {
#pragma unroll
        for (int j = 0; j < 4; ++j) { e[i][j] = __expf(v[i][j] - m); sum += e[i][j]; }
    }
#pragma unroll
    for (int s = 1; s < 64; s <<= 1) sum += __shfl_xor(sum, s, 64);
    float li = 1.f / sum;
    u16* atrow = AT + ((long long)b * TT + t) * NN;
#pragma unroll
    for (int i = 0; i < 8; ++i) {
        ushort4 pk;
        pk.x = f2bf(e[i][0] * li); pk.y = f2bf(e[i][1] * li);
        pk.z = f2bf(e[i][2] * li); pk.w = f2bf(e[i][3] * li);
        ((ushort4*)atrow)[i * 64 + lane] = pk;
    }
    if (lane == 0) { Mv[(long long)b * TT + t] = m; Li[(long long)b * TT + t] = li; }
}

// In-place paired-tile transpose of S (d_out A region): St[t][n] -> A[n][t],
// applying A = exp(s - m[t]) * linv[t] on the fly.
__global__ void transpose_apply(float* S, const float* Mv, const float* Li) {
    int b = blockIdx.y;
    int p = blockIdx.x;
    int i = (int)((sqrtf(8.f * p + 1.f) - 1.f) * 0.5f);
    while ((i + 1) * (i + 2) / 2 <= p) ++i;
    while (i * (i + 1) / 2 > p) --i;
    int j = p - i * (i + 1) / 2;
    float* Sb = S + (long long)b * NN * TT;
    __shared__ float TA[32][33], TB[32][33];
    int tx = threadIdx.x, ty = threadIdx.y;
#pragma unroll
    for (int k = 0; k < 4; ++k) {
        int r = ty + k * 8;
        TA[r][tx] = Sb[(long long)(i * 32 + r) * TT + j * 32 + tx];
        TB[r][tx] = Sb[(long long)(j * 32 + r) * TT + i * 32 + tx];
    }
    __syncthreads();
    float mA = Mv[(long long)b * TT + j * 32 + tx];
    float lA = Li[(long long)b * TT + j * 32 + tx];
    float mB = Mv[(long long)b * TT + i * 32 + tx];
    float lB = Li[(long long)b * TT + i * 32 + tx];
#pragma unroll
    for (int k = 0; k < 4; ++k) {
        int r = ty + k * 8;
        Sb[(long long)(i * 32 + r) * TT + j * 32 + tx] = __expf(TB[tx][r] - mA) * lA;
        Sb[(long long)(j * 32 + r) * TT + i * 32 + tx] = __expf(TA[tx][r] - mB) * lB;
    }
}

// ---------------- host orchestration ----------------

extern "C" void kernel_launch(void* const* d_in, const int* in_sizes, int n_in,
                              void* d_out, int out_size, void* d_ws, size_t ws_size,
                              hipStream_t stream) {
    const float* in_s        = (const float*)d_in[0];
    const float* in_t        = (const float*)d_in[1];
    const float* c_t         = (const float*)d_in[2];
    const float* enc_start_w = (const float*)d_in[3];
    const float* enc_start_b = (const float*)d_in[4];
    const float* glu_w       = (const float*)d_in[5];
    const float* glu_b       = (const float*)d_in[6];
    const float* enc_end_w   = (const float*)d_in[7];
    const float* enc_end_b   = (const float*)d_in[8];
    const float* wc_pre      = (const float*)d_in[9];
    const float* w_pre       = (const float*)d_in[10];
    const float* b_pre       = (const float*)d_in[11];
    const float* wc_post     = (const float*)d_in[12];
    const float* w_post      = (const float*)d_in[13];
    const float* b_post      = (const float*)d_in[14];

    // workspace layout
    char* w = (char*)d_ws;
    u16* wglu   = (u16*)w; w += 8LL * 5 * 1024 * 512 * 2;
    u16* wstart = (u16*)w; w += 512LL * 256 * 2;
    u16* wend   = (u16*)w; w += 1024LL * 512 * 2;
    u16* wpre   = (u16*)w; w += 512LL * 256 * 2;
    u16* wpost  = (u16*)w; w += 256LL * 1024 * 2;
    u16* XS     = (u16*)w; w += (long long)BB * NN * 256 * 2;
    u16* XT     = (u16*)w; w += (long long)BB * TT * 256 * 2;
    u16* h0     = (u16*)w; w += (long long)BB * HROWS * 512 * 2;
    u16* h1     = (u16*)w; w += (long long)BB * HROWS * 512 * 2;
    u16* Kb     = (u16*)w; w += (long long)BB * NN * 512 * 2;
    u16* Vb     = (u16*)w; w += (long long)BB * 512 * NN * 2;
    u16* Rc     = (u16*)w; w += (long long)BB * TT * 1024 * 2;
    u16* ATb    = (u16*)w; w += (long long)BB * TT * NN * 2;
    float* qbias = (float*)w; w += 16LL * 512 * 4;
    float* ybias = (float*)w; w += 16LL * 256 * 4;
    float* Mv    = (float*)w; w += 16LL * 2048 * 4;
    float* Li    = (float*)w; w += 16LL * 2048 * 4;
    float* biasP = (float*)w; w += 8LL * 1024 * 4;
    if ((size_t)(w - (char*)d_ws) > ws_size) return;  // insufficient scratch — bail

    float* yout = (float*)d_out;
    float* Sreg = yout + Y_SIZE;   // scores St[t][n] then final A[n][t] (in place)

    // ---- conversions / setup ----
    cvt_glu<<<(8LL * 5 * 1024 * 512 + 255) / 256, 256, 0, stream>>>(glu_w, wglu);
    perm_bias<<<(8 * 1024 + 255) / 256, 256, 0, stream>>>(glu_b, biasP);
    cvt_pad<<<(512 * 256 + 255) / 256, 256, 0, stream>>>(enc_start_w, wstart, 512, 240, 512, 256);
    cvt_pad<<<(1024 * 512 + 255) / 256, 256, 0, stream>>>(enc_end_w, wend, 1024, 512, 1024, 512);
    cvt_pad<<<(512 * 256 + 255) / 256, 256, 0, stream>>>(w_pre, wpre, 512, 240, 512, 256);
    cvt_pad<<<(256 * 1024 + 255) / 256, 256, 0, stream>>>(w_post, wpost, 240, 1024, 256, 1024);
    transpose_in<<<dim3(NN / 32, 256 / 32, BB), dim3(32, 32), 0, stream>>>(in_s, XS, 240, 256, NN);
    transpose_in<<<dim3(TT / 32, 256 / 32, BB), dim3(32, 32), 0, stream>>>(in_t, XT, 240, 256, TT);
    zero_pads<<<((long long)BB * 128 * 512 + 255) / 256, 256, 0, stream>>>(h0);
    zero_pads<<<((long long)BB * 128 * 512 + 255) / 256, 256, 0, stream>>>(h1);
    prebias_kernel<<<16, 256, 0, stream>>>(c_t, wc_pre, w_pre, b_pre, qbias);
    postbias_kernel<<<16, 256, 0, stream>>>(c_t, wc_post, w_post, b_post, ybias);

    // ---- enc_start: XS[2048][256] x wstart[512][256] -> h0 bf16 [n][512] ----
    {
        GemmP p{}; p.A = XS; p.a_bstride = (long long)NN * 256; p.lda = 256;
        p.Bw = wstart; p.b_bstride = 0; p.b_tapstride = 0; p.ldb = 256;
        p.ntaps = 1; p.shift0 = 0; p.dshift = 0; p.Kt = 256;
        p.out = h0 + HPAD * 512; p.o_bstride = (long long)HROWS * 512; p.ldc = 512;
        p.bias = enc_start_b; p.bias_bstride = 0; p.scale = 1.f; p.store_ncols = 512;
        gemm_kernel<1><<<dim3(16, 4, 16), 256, 0, stream>>>(p);
    }

    // ---- 8 GLU blocks (fused epilogue) ----
    const int dils[8] = {1, 3, 9, 27, 1, 3, 9, 27};
    u16* hin = h0; u16* hout = h1;
    for (int l = 0; l < 8; ++l) {
        GemmP q{}; q.A = hin + HPAD * 512; q.a_bstride = (long long)HROWS * 512; q.lda = 512;
        q.Bw = wglu + (long long)l * 5 * 1024 * 512; q.b_bstride = 0;
        q.b_tapstride = 1024LL * 512; q.ldb = 512;
        q.ntaps = 5; q.shift0 = -2 * dils[l]; q.dshift = dils[l]; q.Kt = 512;
        q.out = hout + HPAD * 512; q.o_bstride = (long long)HROWS * 512; q.ldc = 512;
        q.bias = biasP + l * 1024; q.bias_bstride = 0; q.scale = 1.f; q.store_ncols = 1024;
        gemm_kernel<4><<<dim3(16, 8, 16), 256, 0, stream>>>(q);
        u16* tmp = hin; hin = hout; hout = tmp;
    }

    // ---- enc_end: K half (bf16 [n][512]) and V half (bf16 transposed [512][n]) ----
    {
        GemmP p{}; p.A = hin + HPAD * 512; p.a_bstride = (long long)HROWS * 512; p.lda = 512;
        p.Bw = wend; p.b_bstride = 0; p.b_tapstride = 0; p.ldb = 512;
        p.ntaps = 1; p.shift0 = 0; p.dshift = 0; p.Kt = 512;
        p.out = Kb; p.o_bstride = (long long)NN * 512; p.ldc = 512;
        p.bias = enc_end_b; p.bias_bstride = 0; p.scale = 1.f; p.store_ncols = 512;
        gemm_kernel<1><<<dim3(16, 4, 16), 256, 0, stream>>>(p);
        GemmP v = p;
        v.Bw = wend + 512LL * 512; v.bias = enc_end_b + 512;
        v.out = Vb; v.o_bstride = 512LL * NN; v.ldc = NN;
        gemm_kernel<3><<<dim3(16, 4, 16), 256, 0, stream>>>(v);
    }

    // ---- pre-decoder: Q into Rc columns 512..1023 ----
    {
        GemmP p{}; p.A = XT; p.a_bstride = (long long)TT * 256; p.lda = 256;
        p.Bw = wpre; p.b_bstride = 0; p.b_tapstride = 0; p.ldb = 256;
        p.ntaps = 1; p.shift0 = 0; p.dshift = 0; p.Kt = 256;
        p.out = Rc + 512; p.o_bstride = (long long)TT * 1024; p.ldc = 1024;
        p.bias = qbias; p.bias_bstride = 512; p.scale = 1.f; p.store_ncols = 512;
        gemm_kernel<1><<<dim3(16, 4, 16), 256, 0, stream>>>(p);
    }

    // ---- scores (swapped): St[t][n] = Q[t]·K[n] / sqrt(d), f32 into d_out A region ----
    {
        GemmP p{}; p.A = Rc + 512; p.a_bstride = (long long)TT * 1024; p.lda = 1024;
        p.Bw = Kb; p.b_bstride = (long long)NN * 512; p.b_tapstride = 0; p.ldb = 512;
        p.ntaps = 1; p.shift0 = 0; p.dshift = 0; p.Kt = 512;
        p.out = Sreg; p.o_bstride = (long long)TT * NN; p.ldc = NN;
        p.bias = nullptr; p.bias_bstride = 0; p.scale = 0.04419417382415922f; // 1/sqrt(512)
        p.store_ncols = NN;
        gemm_kernel<0><<<dim3(16, 16, 16), 256, 0, stream>>>(p);
    }

    // ---- softmax over n: row-wise on St, write AT bf16 + m/linv ----
    softmax_rows<<<dim3(TT / 4, BB), 256, 0, stream>>>(Sreg, ATb, Mv, Li);
    // ---- in-place transposed normalize: St -> A[n][t] f32 (final output) ----
    transpose_apply<<<dim3(64 * 65 / 2, BB), dim3(32, 8), 0, stream>>>(Sreg, Mv, Li);

    // ---- R = V x A  (C[t][d] = sum_n AT[t][n] * V[d][n]) into Rc cols 0..511 ----
    {
        GemmP p{}; p.A = ATb; p.a_bstride = (long long)TT * NN; p.lda = NN;
        p.Bw = Vb; p.b_bstride = 512LL * NN; p.b_tapstride = 0; p.ldb = NN;
        p.ntaps = 1; p.shift0 = 0; p.dshift = 0; p.Kt = NN;
        p.out = Rc; p.o_bstride = (long long)TT * 1024; p.ldc = 1024;
        p.bias = nullptr; p.bias_bstride = 0; p.scale = 1.f; p.store_ncols = 512;
        gemm_kernel<1><<<dim3(16, 4, 16), 256, 0, stream>>>(p);
    }

    // ---- post-decoder: Rc[t][1024] x wpost -> y f32 [b][240][t] (transposed store) ----
    {
        GemmP p{}; p.A = Rc; p.a_bstride = (long long)TT * 1024; p.lda = 1024;
        p.Bw = wpost; p.b_bstride = 0; p.b_tapstride = 0; p.ldb = 1024;
        p.ntaps = 1; p.shift0 = 0; p.dshift = 0; p.Kt = 1024;
        p.out = yout; p.o_bstride = (long long)DIN * TT; p.ldc = TT;
        p.bias = ybias; p.bias_bstride = 240; p.scale = 1.f; p.store_ncols = 240;
        gemm_kernel<2><<<dim3(16, 2, 16), 256, 0, stream>>>(p);
    }
}

// Round 3
// 2054.379 us; speedup vs baseline: 1.3764x; 1.0547x over previous
//
#include <hip/hip_runtime.h>
#include <cstdint>
#include <cstddef>

typedef unsigned short u16;
typedef __attribute__((ext_vector_type(8))) short short8;
typedef __attribute__((ext_vector_type(4))) float f32x4;

static constexpr int BB = 16, DIN = 240, NN = 2048, TT = 2048;
static constexpr long long Y_SIZE = (long long)BB * DIN * TT;          // 7,864,320 f32
static constexpr float SQRT_HALF_F = 0.70710678118654752440f;
static constexpr int HPAD = 64;                 // zero-pad rows each side of h (max shift 54)
static constexpr int HROWS = NN + 2 * HPAD;     // 2176

#define DEVI __device__ __forceinline__

DEVI u16 f2bf(float f) {
    unsigned u = __builtin_bit_cast(unsigned, f);
    u += 0x7FFFu + ((u >> 16) & 1u);
    return (u16)(u >> 16);
}
DEVI float bf2f(u16 h) {
    unsigned u = ((unsigned)h) << 16;
    return __builtin_bit_cast(float, u);
}

DEVI void gld16(const void* g, const void* l) {
    __builtin_amdgcn_global_load_lds(
        (const __attribute__((address_space(1))) unsigned int*)g,
        (__attribute__((address_space(3))) unsigned int*)l, 16, 0, 0);
}

// GLU column permutation for the 256-wide tile geometry: GEMM col g -> conv output
// channel. Within each wave's 64-col span, fragments n={0,2} are "a" channels and
// n={1,3} the matching gate "b" channels at +16 GEMM cols.
DEVI int glu_perm(int g) {
    int tile = g >> 8, r = g & 255;
    int wcq = r >> 6, r2 = r & 63;
    int n = r2 >> 4, fr = r2 & 15;
    return tile * 128 + wcq * 32 + (n >> 1) * 16 + fr + (n & 1) * 512;
}

// ---------------- GEMM params ----------------
// C[row][col] = scale * sum_taps sum_k A[row+shift][k] * B[col][k]  (+bias)
struct GemmP {
    const u16* A; long long a_bstride; int lda;
    const u16* Bw; long long b_bstride; long long b_tapstride; int ldb;
    int ntaps; int shift0; int dshift; int Kt; int ks_log2;
    void* out; long long o_bstride; int ldc;
    const float* bias; int bias_bstride;
    float scale;
    int store_ncols;
};

// =============== 256x256 deep-pipelined MFMA GEMM (BK=64, 8 waves) ===============
// OUTK: 1 = bf16 row-major, col-bias (+scale). 4 = GLU fused epilogue.
//       5 = bf16 row-major, ROW-bias.
template <int OUTK>
__global__ __launch_bounds__(512, 2)
void gemm256(GemmP p, int tilesM, int tilesN) {
    __shared__ __align__(16) u16 As[2][256 * 64];
    __shared__ __align__(16) u16 Bs[2][256 * 64];
    const int tid = threadIdx.x;
    const int lane = tid & 63;
    const int wv = tid >> 6;
    const int wr = wv >> 2, wcq = wv & 3;          // 2 x 4 wave grid
    const int fr = lane & 15, fq = lane >> 4;

    // bijective XCD-aware block swizzle (grid always a multiple of 8)
    const int nwg = gridDim.x;
    int widx = (blockIdx.x & 7) * (nwg >> 3) + (blockIdx.x >> 3);
    const int mt = widx % tilesM; widx /= tilesM;
    const int nt = widx % tilesN;
    const int bz = widx / tilesN;
    const int n0 = mt * 256, c0 = nt * 256;

    const u16* Abase = p.A + (long long)bz * p.a_bstride;
    const u16* Bbase = p.Bw + (long long)bz * p.b_bstride;
    const int kmask = (1 << p.ks_log2) - 1;
    const int tot = p.ntaps << p.ks_log2;

    f32x4 acc[8][4];
#pragma unroll
    for (int m = 0; m < 8; ++m)
#pragma unroll
        for (int n = 0; n < 4; ++n) acc[m][n] = (f32x4){0.f, 0.f, 0.f, 0.f};

    const int row0 = tid >> 3, j0 = tid & 7;      // staging: chunk c = i*512+tid
    const int wb8 = (tid & ~63) << 3;             // wave-uniform LDS u16 base

    // stage K-tile t into buffer buf: pre-swizzled global source, linear LDS dest
    auto STAGE = [&](int t, int buf) {
        const int tap = t >> p.ks_log2;
        const int ks = (t & kmask) << 6;
        const int shift = p.shift0 + tap * p.dshift;
        const u16* a = Abase + (long long)(n0 + shift) * p.lda + ks;
        const u16* b = Bbase + (long long)tap * p.b_tapstride + (long long)c0 * p.ldb + ks;
#pragma unroll
        for (int i = 0; i < 4; ++i) {
            int row = i * 64 + row0;
            int js = (j0 ^ (row & 7)) << 3;
            gld16(a + (long long)row * p.lda + js, &As[buf][(i << 12) + wb8]);
            gld16(b + (long long)row * p.ldb + js, &Bs[buf][(i << 12) + wb8]);
        }
    };

    STAGE(0, 0);
    if (tot > 1) STAGE(1, 1);

    for (int t = 0; t < tot; ++t) {
        if (t + 1 < tot) asm volatile("s_waitcnt vmcnt(8)" ::: "memory");
        else             asm volatile("s_waitcnt vmcnt(0)" ::: "memory");
        __builtin_amdgcn_s_barrier();
        asm volatile("" ::: "memory");
        const u16* Ab = As[t & 1];
        const u16* Bb = Bs[t & 1];
#pragma unroll
        for (int kk = 0; kk < 2; ++kk) {
            const int slot = kk * 4 + fq;
            short8 af[8], bfv[4];
#pragma unroll
            for (int m = 0; m < 8; ++m) {
                int row = wr * 128 + m * 16 + fr;
                af[m] = *(const short8*)&Ab[row * 64 + ((slot ^ (row & 7)) << 3)];
            }
#pragma unroll
            for (int n = 0; n < 4; ++n) {
                int col = wcq * 64 + n * 16 + fr;
                bfv[n] = *(const short8*)&Bb[col * 64 + ((slot ^ (col & 7)) << 3)];
            }
            __builtin_amdgcn_s_setprio(1);
#pragma unroll
            for (int m = 0; m < 8; ++m)
#pragma unroll
                for (int n = 0; n < 4; ++n)
                    acc[m][n] = __builtin_amdgcn_mfma_f32_16x16x32_bf16(
                        af[m], bfv[n], acc[m][n], 0, 0, 0);
            __builtin_amdgcn_s_setprio(0);
        }
        asm volatile("" ::: "memory");
        __builtin_amdgcn_s_barrier();
        if (t + 2 < tot) STAGE(t + 2, t & 1);
    }

    if constexpr (OUTK == 4) {
        // GLU: a,b pairs in adjacent 16-col fragments; residual h_in via A operand.
        const float* bp = p.bias;
#pragma unroll
        for (int m = 0; m < 8; ++m) {
#pragma unroll
            for (int pr = 0; pr < 2; ++pr) {
                int ca = c0 + wcq * 64 + (2 * pr) * 16 + fr;
                int chan = (c0 >> 1) + wcq * 32 + pr * 16 + fr;
                float biasa = bp[ca], biasb = bp[ca + 16];
#pragma unroll
                for (int r = 0; r < 4; ++r) {
                    int row = n0 + wr * 128 + m * 16 + fq * 4 + r;
                    float a = acc[m][2 * pr][r] + biasa;
                    float bq = acc[m][2 * pr + 1][r] + biasb;
                    float sig = 1.f / (1.f + __expf(-bq));
                    float h = bf2f(Abase[(long long)row * p.lda + chan]);
                    ((u16*)p.out)[(long long)bz * p.o_bstride + (long long)row * p.ldc + chan]
                        = f2bf((h + a * sig) * SQRT_HALF_F);
                }
            }
        }
        return;
    } else {
        const float* bias = p.bias ? p.bias + (long long)bz * p.bias_bstride : nullptr;
#pragma unroll
        for (int m = 0; m < 8; ++m) {
#pragma unroll
            for (int n = 0; n < 4; ++n) {
                int col = c0 + wcq * 64 + n * 16 + fr;
                float cb = (OUTK == 1 && bias) ? bias[col] : 0.f;
#pragma unroll
                for (int r = 0; r < 4; ++r) {
                    int row = n0 + wr * 128 + m * 16 + fq * 4 + r;
                    float v = acc[m][n][r] * p.scale + cb;
                    if (OUTK == 5) v += bias[row];
                    ((u16*)p.out)[(long long)bz * p.o_bstride + (long long)row * p.ldc + col]
                        = f2bf(v);
                }
            }
        }
    }
}

// =============== 128x128 GEMM (kept for the N=240 transposed-f32 post GEMM) ===============
template <int OUTK>
__global__ __launch_bounds__(256, 2)
void gemm_kernel(GemmP p) {
    __shared__ u16 As[128 * 64];
    __shared__ u16 Bs[128 * 64];
    const int tid = threadIdx.x;
    const int lane = tid & 63, wv = tid >> 6;
    const int wr = wv >> 1, wc = wv & 1;
    const int bz = blockIdx.z;
    const int n0 = blockIdx.x * 128;
    const int c0 = blockIdx.y * 128;
    const u16* Abase = p.A + (long long)bz * p.a_bstride;
    const u16* Bbase = p.Bw + (long long)bz * p.b_bstride;

    f32x4 acc[4][4];
#pragma unroll
    for (int i = 0; i < 4; ++i)
#pragma unroll
        for (int j = 0; j < 4; ++j) acc[i][j] = (f32x4){0.f, 0.f, 0.f, 0.f};

    const int ksteps = p.Kt >> 6;
    const int tot = p.ntaps * ksteps;
    const int srow = lane >> 3;
    const int scol = (lane & 7) * 8;
    const int fr = lane & 15;
    const int fk = (lane >> 4) * 8;

    for (int t = 0; t < tot; ++t) {
        const int tap = t / ksteps;
        const int ks = (t - tap * ksteps) << 6;
        const int shift = p.shift0 + tap * p.dshift;
        __syncthreads();
        {
            const u16* asrc = Abase + (long long)(n0 + shift) * p.lda + ks;
#pragma unroll
            for (int c = 0; c < 4; ++c) {
                int chunk = wv * 4 + c;
                int row = chunk * 8 + srow;
                gld16(asrc + (long long)row * p.lda + scol, &As[chunk * 512]);
            }
            const u16* bsrc = Bbase + (long long)tap * p.b_tapstride + (long long)c0 * p.ldb + ks;
#pragma unroll
            for (int c = 0; c < 4; ++c) {
                int chunk = wv * 4 + c;
                int row = chunk * 8 + srow;
                gld16(bsrc + (long long)row * p.ldb + scol, &Bs[chunk * 512]);
            }
        }
        asm volatile("s_waitcnt vmcnt(0)" ::: "memory");
        __syncthreads();
#pragma unroll
        for (int kk = 0; kk < 2; ++kk) {
            short8 af[4], bfr[4];
#pragma unroll
            for (int m = 0; m < 4; ++m) {
                int arow = wr * 64 + m * 16 + fr;
                af[m] = *(const short8*)&As[arow * 64 + kk * 32 + fk];
            }
#pragma unroll
            for (int nn2 = 0; nn2 < 4; ++nn2) {
                int brow = wc * 64 + nn2 * 16 + fr;
                bfr[nn2] = *(const short8*)&Bs[brow * 64 + kk * 32 + fk];
            }
#pragma unroll
            for (int m = 0; m < 4; ++m)
#pragma unroll
                for (int nn2 = 0; nn2 < 4; ++nn2)
                    acc[m][nn2] = __builtin_amdgcn_mfma_f32_16x16x32_bf16(
                        af[m], bfr[nn2], acc[m][nn2], 0, 0, 0);
        }
    }

    const float* bias = p.bias ? p.bias + (long long)bz * p.bias_bstride : nullptr;
#pragma unroll
    for (int m = 0; m < 4; ++m) {
#pragma unroll
        for (int nn2 = 0; nn2 < 4; ++nn2) {
#pragma unroll
            for (int r = 0; r < 4; ++r) {
                int row = n0 + wr * 64 + m * 16 + ((lane >> 4) << 2) + r;
                int col = c0 + wc * 64 + nn2 * 16 + (lane & 15);
                if (col >= p.store_ncols) continue;
                float v = acc[m][nn2][r] * p.scale;
                if (bias) v += bias[col];
                long long off = (OUTK == 0 || OUTK == 1)
                                    ? (long long)row * p.ldc + col
                                    : (long long)col * p.ldc + row;
                long long idx = (long long)bz * p.o_bstride + off;
                if (OUTK == 0 || OUTK == 2) ((float*)p.out)[idx] = v;
                else ((u16*)p.out)[idx] = f2bf(v);
            }
        }
    }
}

// ---------------- elementwise / helper kernels ----------------

__global__ void cvt_glu(const float* src, u16* dst) {
    long long t = (long long)blockIdx.x * blockDim.x + threadIdx.x;
    const long long total = 8LL * 5 * 1024 * 512;
    if (t >= total) return;
    int i = (int)(t % 512); long long r = t / 512;
    int g = (int)(r % 1024); r /= 1024;
    int k = (int)(r % 5); int l = (int)(r / 5);
    int o = glu_perm(g);
    dst[t] = f2bf(src[(((long long)l * 1024 + o) * 512 + i) * 5 + k]);
}

__global__ void perm_bias(const float* gb, float* biasP) {
    int t = blockIdx.x * 256 + threadIdx.x;
    if (t >= 8 * 1024) return;
    int g = t & 1023, l = t >> 10;
    biasP[t] = gb[l * 1024 + glu_perm(g)];
}

__global__ void cvt_pad(const float* src, u16* dst, int Os, int Is, int Od, int Id) {
    long long t = (long long)blockIdx.x * blockDim.x + threadIdx.x;
    if (t >= (long long)Od * Id) return;
    int i = (int)(t % Id); int o = (int)(t / Id);
    float v = (o < Os && i < Is) ? src[(long long)o * Is + i] : 0.f;
    dst[t] = f2bf(v);
}

// src [b][Csrc][Len] f32 -> dst [b][Len][Cdst] bf16 (zero-pad channels)
__global__ void transpose_in(const float* src, u16* dst, int Csrc, int Cdst, int Len) {
    __shared__ float tile[32][33];
    int b = blockIdx.z;
    int n0 = blockIdx.x * 32, c0 = blockIdx.y * 32;
    int tx = threadIdx.x, ty = threadIdx.y;
    int c = c0 + ty, n = n0 + tx;
    float v = 0.f;
    if (c < Csrc) v = src[((long long)b * Csrc + c) * Len + n];
    tile[ty][tx] = v;
    __syncthreads();
    dst[((long long)b * Len + (n0 + ty)) * Cdst + (c0 + tx)] = f2bf(tile[tx][ty]);
}

__global__ void zero_pads(u16* h) {
    long long t = (long long)blockIdx.x * blockDim.x + threadIdx.x;
    const long long total = (long long)BB * 128 * 512;
    if (t >= total) return;
    int c = (int)(t % 512); long long r = t / 512;
    int rr = (int)(r % 128); int b = (int)(r / 128);
    int row = rr < HPAD ? rr : (HROWS - 128 + rr);
    h[((long long)b * HROWS + row) * 512 + c] = 0;
}

__global__ void prebias_kernel(const float* ct, const float* wcpre, const float* wpre,
                               const float* bpre, float* qbias) {
    __shared__ float s[240];
    int b = blockIdx.x; int tid = threadIdx.x;
    if (tid < 240) {
        float a = 0.f;
        for (int c = 0; c < 8; ++c) a += ct[b * 8 + c] * wcpre[c * 240 + tid];
        s[tid] = a;
    }
    __syncthreads();
    for (int o = tid; o < 512; o += 256) {
        float a = bpre[o];
        for (int d0 = 0; d0 < 240; ++d0) a += wpre[o * 240 + d0] * s[d0];
        qbias[b * 512 + o] = a;
    }
}

__global__ void postbias_kernel(const float* ct, const float* wcpost, const float* wpost,
                                const float* bpost, float* ybias) {
    __shared__ float s[1024];
    int b = blockIdx.x; int tid = threadIdx.x;
    for (int e = tid; e < 1024; e += 256) {
        float a = 0.f;
        for (int c = 0; c < 8; ++c) a += ct[b * 8 + c] * wcpost[c * 1024 + e];
        s[e] = a;
    }
    __syncthreads();
    if (tid < 240) {
        float a = bpost[tid];
        for (int e = 0; e < 1024; ++e) a += wpost[tid * 1024 + e] * s[e];
        ybias[b * 240 + tid] = a;
    }
}

// One wave per (b,t): read bf16 score row, softmax, write normalized bf16 AT row.
__global__ __launch_bounds__(256)
void softmax_rows(const u16* St, u16* AT) {
    int b = blockIdx.y;
    int t = blockIdx.x * 4 + (threadIdx.x >> 6);
    int lane = threadIdx.x & 63;
    const u16* row = St + ((long long)b * TT + t) * NN;
    short8 v[4];
#pragma unroll
    for (int i = 0; i < 4; ++i) v[i] = ((const short8*)row)[i * 64 + lane];
    float f[32];
#pragma unroll
    for (int i = 0; i < 4; ++i)
#pragma unroll
        for (int j = 0; j < 8; ++j) f[i * 8 + j] = bf2f((u16)v[i][j]);
    float m = -3.4e38f;
#pragma unroll
    for (int i = 0; i < 32; ++i) m = fmaxf(m, f[i]);
#pragma unroll
    for (int s = 1; s < 64; s <<= 1) m = fmaxf(m, __shfl_xor(m, s, 64));
    float sum = 0.f;
#pragma unroll
    for (int i = 0; i < 32; ++i) { f[i] = __expf(f[i] - m); sum += f[i]; }
#pragma unroll
    for (int s = 1; s < 64; s <<= 1) sum += __shfl_xor(sum, s, 64);
    float li = 1.f / sum;
    u16* atrow = AT + ((long long)b * TT + t) * NN;
#pragma unroll
    for (int i = 0; i < 4; ++i) {
        short8 pk;
#pragma unroll
        for (int j = 0; j < 8; ++j) pk[j] = (short)f2bf(f[i * 8 + j] * li);
        ((short8*)atrow)[i * 64 + lane] = pk;
    }
}

// AT bf16 [b][t][n] -> A f32 [b][n][t] (final output region)
__global__ void transpose_out(const u16* AT, float* A) {
    __shared__ float tile[32][33];
    int b = blockIdx.z;
    int n0 = blockIdx.x * 32, t0 = blockIdx.y * 32;
    int tx = threadIdx.x, ty = threadIdx.y;
#pragma unroll
    for (int k = 0; k < 4; ++k) {
        int t = t0 + ty + k * 8;
        tile[ty + k * 8][tx] = bf2f(AT[((long long)b * TT + t) * NN + n0 + tx]);
    }
    __syncthreads();
#pragma unroll
    for (int k = 0; k < 4; ++k) {
        int n = n0 + ty + k * 8;
        A[((long long)b * NN + n) * TT + t0 + tx] = tile[tx][ty + k * 8];
    }
}

// ---------------- host orchestration ----------------

static inline int ilog2(int x) { int r = 0; while ((1 << r) < x) ++r; return r; }

extern "C" void kernel_launch(void* const* d_in, const int* in_sizes, int n_in,
                              void* d_out, int out_size, void* d_ws, size_t ws_size,
                              hipStream_t stream) {
    const float* in_s        = (const float*)d_in[0];
    const float* in_t        = (const float*)d_in[1];
    const float* c_t         = (const float*)d_in[2];
    const float* enc_start_w = (const float*)d_in[3];
    const float* enc_start_b = (const float*)d_in[4];
    const float* glu_w       = (const float*)d_in[5];
    const float* glu_b       = (const float*)d_in[6];
    const float* enc_end_w   = (const float*)d_in[7];
    const float* enc_end_b   = (const float*)d_in[8];
    const float* wc_pre      = (const float*)d_in[9];
    const float* w_pre       = (const float*)d_in[10];
    const float* b_pre       = (const float*)d_in[11];
    const float* wc_post     = (const float*)d_in[12];
    const float* w_post      = (const float*)d_in[13];
    const float* b_post      = (const float*)d_in[14];

    // workspace layout
    char* w = (char*)d_ws;
    u16* wglu   = (u16*)w; w += 8LL * 5 * 1024 * 512 * 2;
    u16* wstart = (u16*)w; w += 512LL * 256 * 2;
    u16* wend   = (u16*)w; w += 1024LL * 512 * 2;
    u16* wpre   = (u16*)w; w += 512LL * 256 * 2;
    u16* wpost  = (u16*)w; w += 256LL * 1024 * 2;
    u16* XS     = (u16*)w; w += (long long)BB * NN * 256 * 2;
    u16* XT     = (u16*)w; w += (long long)BB * TT * 256 * 2;
    u16* h0     = (u16*)w; w += (long long)BB * HROWS * 512 * 2;
    u16* h1     = (u16*)w; w += (long long)BB * HROWS * 512 * 2;
    u16* Kb     = (u16*)w; w += (long long)BB * NN * 512 * 2;
    u16* Vb     = (u16*)w; w += (long long)BB * 512 * NN * 2;
    u16* Rc     = (u16*)w; w += (long long)BB * TT * 1024 * 2;
    u16* ATb    = (u16*)w; w += (long long)BB * TT * NN * 2;
    float* qbias = (float*)w; w += 16LL * 512 * 4;
    float* ybias = (float*)w; w += 16LL * 256 * 4;
    float* biasP = (float*)w; w += 8LL * 1024 * 4;
    if ((size_t)(w - (char*)d_ws) > ws_size) return;  // insufficient scratch — bail

    float* yout = (float*)d_out;
    float* Areg = yout + Y_SIZE;       // final A f32 [b][n][t]
    u16* Sbf = (u16*)Areg;             // transient bf16 scores [b][t][n] (first half of A region)

    // ---- conversions / setup ----
    cvt_glu<<<(8LL * 5 * 1024 * 512 + 255) / 256, 256, 0, stream>>>(glu_w, wglu);
    perm_bias<<<(8 * 1024 + 255) / 256, 256, 0, stream>>>(glu_b, biasP);
    cvt_pad<<<(512 * 256 + 255) / 256, 256, 0, stream>>>(enc_start_w, wstart, 512, 240, 512, 256);
    cvt_pad<<<(1024 * 512 + 255) / 256, 256, 0, stream>>>(enc_end_w, wend, 1024, 512, 1024, 512);
    cvt_pad<<<(512 * 256 + 255) / 256, 256, 0, stream>>>(w_pre, wpre, 512, 240, 512, 256);
    cvt_pad<<<(256 * 1024 + 255) / 256, 256, 0, stream>>>(w_post, wpost, 240, 1024, 256, 1024);
    transpose_in<<<dim3(NN / 32, 256 / 32, BB), dim3(32, 32), 0, stream>>>(in_s, XS, 240, 256, NN);
    transpose_in<<<dim3(TT / 32, 256 / 32, BB), dim3(32, 32), 0, stream>>>(in_t, XT, 240, 256, TT);
    zero_pads<<<((long long)BB * 128 * 512 + 255) / 256, 256, 0, stream>>>(h0);
    zero_pads<<<((long long)BB * 128 * 512 + 255) / 256, 256, 0, stream>>>(h1);
    prebias_kernel<<<16, 256, 0, stream>>>(c_t, wc_pre, w_pre, b_pre, qbias);
    postbias_kernel<<<16, 256, 0, stream>>>(c_t, wc_post, w_post, b_post, ybias);

    // ---- enc_start: XS[2048][256] x wstart[512][256] -> h0 bf16 [n][512] ----
    {
        GemmP p{}; p.A = XS; p.a_bstride = (long long)NN * 256; p.lda = 256;
        p.Bw = wstart; p.b_bstride = 0; p.b_tapstride = 0; p.ldb = 256;
        p.ntaps = 1; p.shift0 = 0; p.dshift = 0; p.Kt = 256; p.ks_log2 = 2;
        p.out = h0 + HPAD * 512; p.o_bstride = (long long)HROWS * 512; p.ldc = 512;
        p.bias = enc_start_b; p.bias_bstride = 0; p.scale = 1.f; p.store_ncols = 512;
        gemm256<1><<<8 * 2 * 16, 512, 0, stream>>>(p, 8, 2);
    }

    // ---- 8 GLU blocks (fused epilogue) ----
    const int dils[8] = {1, 3, 9, 27, 1, 3, 9, 27};
    u16* hin = h0; u16* hout = h1;
    for (int l = 0; l < 8; ++l) {
        GemmP q{}; q.A = hin + HPAD * 512; q.a_bstride = (long long)HROWS * 512; q.lda = 512;
        q.Bw = wglu + (long long)l * 5 * 1024 * 512; q.b_bstride = 0;
        q.b_tapstride = 1024LL * 512; q.ldb = 512;
        q.ntaps = 5; q.shift0 = -2 * dils[l]; q.dshift = dils[l]; q.Kt = 512; q.ks_log2 = 3;
        q.out = hout + HPAD * 512; q.o_bstride = (long long)HROWS * 512; q.ldc = 512;
        q.bias = biasP + l * 1024; q.bias_bstride = 0; q.scale = 1.f; q.store_ncols = 1024;
        gemm256<4><<<8 * 4 * 16, 512, 0, stream>>>(q, 8, 4);
        u16* tmp = hin; hin = hout; hout = tmp;
    }

    // ---- enc_end K: h[n][512] x wend_K[512][512] -> Kb bf16 [n][512] ----
    {
        GemmP p{}; p.A = hin + HPAD * 512; p.a_bstride = (long long)HROWS * 512; p.lda = 512;
        p.Bw = wend; p.b_bstride = 0; p.b_tapstride = 0; p.ldb = 512;
        p.ntaps = 1; p.shift0 = 0; p.dshift = 0; p.Kt = 512; p.ks_log2 = 3;
        p.out = Kb; p.o_bstride = (long long)NN * 512; p.ldc = 512;
        p.bias = enc_end_b; p.bias_bstride = 0; p.scale = 1.f; p.store_ncols = 512;
        gemm256<1><<<8 * 2 * 16, 512, 0, stream>>>(p, 8, 2);
    }
    // ---- enc_end V (operand-swapped): Vb[d][n] = wend_V[d][k] · h[n][k], row-bias ----
    {
        GemmP p{}; p.A = wend + 512LL * 512; p.a_bstride = 0; p.lda = 512;
        p.Bw = hin + HPAD * 512; p.b_bstride = (long long)HROWS * 512; p.b_tapstride = 0; p.ldb = 512;
        p.ntaps = 1; p.shift0 = 0; p.dshift = 0; p.Kt = 512; p.ks_log2 = 3;
        p.out = Vb; p.o_bstride = 512LL * NN; p.ldc = NN;
        p.bias = enc_end_b + 512; p.bias_bstride = 0; p.scale = 1.f; p.store_ncols = NN;
        gemm256<5><<<2 * 8 * 16, 512, 0, stream>>>(p, 2, 8);
    }

    // ---- pre-decoder: Q into Rc columns 512..1023 ----
    {
        GemmP p{}; p.A = XT; p.a_bstride = (long long)TT * 256; p.lda = 256;
        p.Bw = wpre; p.b_bstride = 0; p.b_tapstride = 0; p.ldb = 256;
        p.ntaps = 1; p.shift0 = 0; p.dshift = 0; p.Kt = 256; p.ks_log2 = 2;
        p.out = Rc + 512; p.o_bstride = (long long)TT * 1024; p.ldc = 1024;
        p.bias = qbias; p.bias_bstride = 512; p.scale = 1.f; p.store_ncols = 512;
        gemm256<1><<<8 * 2 * 16, 512, 0, stream>>>(p, 8, 2);
    }

    // ---- scores: St[t][n] = Q[t]·K[n] / sqrt(d), bf16 into Sbf ----
    {
        GemmP p{}; p.A = Rc + 512; p.a_bstride = (long long)TT * 1024; p.lda = 1024;
        p.Bw = Kb; p.b_bstride = (long long)NN * 512; p.b_tapstride = 0; p.ldb = 512;
        p.ntaps = 1; p.shift0 = 0; p.dshift = 0; p.Kt = 512; p.ks_log2 = 3;
        p.out = Sbf; p.o_bstride = (long long)TT * NN; p.ldc = NN;
        p.bias = nullptr; p.bias_bstride = 0; p.scale = 0.04419417382415922f; // 1/sqrt(512)
        p.store_ncols = NN;
        gemm256<1><<<8 * 8 * 16, 512, 0, stream>>>(p, 8, 8);
    }

    // ---- softmax over n (contiguous), normalized AT bf16 ----
    softmax_rows<<<dim3(TT / 4, BB), 256, 0, stream>>>(Sbf, ATb);
    // ---- AT -> final A f32 [n][t] (overwrites dead Sbf region) ----
    transpose_out<<<dim3(NN / 32, TT / 32, BB), dim3(32, 8), 0, stream>>>(ATb, Areg);

    // ---- R = V x A  (C[t][d] = sum_n AT[t][n] * V[d][n]) into Rc cols 0..511 ----
    {
        GemmP p{}; p.A = ATb; p.a_bstride = (long long)TT * NN; p.lda = NN;
        p.Bw = Vb; p.b_bstride = 512LL * NN; p.b_tapstride = 0; p.ldb = NN;
        p.ntaps = 1; p.shift0 = 0; p.dshift = 0; p.Kt = NN; p.ks_log2 = 5;
        p.out = Rc; p.o_bstride = (long long)TT * 1024; p.ldc = 1024;
        p.bias = nullptr; p.bias_bstride = 0; p.scale = 1.f; p.store_ncols = 512;
        gemm256<1><<<8 * 2 * 16, 512, 0, stream>>>(p, 8, 2);
    }

    // ---- post-decoder: Rc[t][1024] x wpost -> y f32 [b][240][t] (transposed store) ----
    {
        GemmP p{}; p.A = Rc; p.a_bstride = (long long)TT * 1024; p.lda = 1024;
        p.Bw = wpost; p.b_bstride = 0; p.b_tapstride = 0; p.ldb = 1024;
        p.ntaps = 1; p.shift0 = 0; p.dshift = 0; p.Kt = 1024; p.ks_log2 = 4;
        p.out = yout; p.o_bstride = (long long)DIN * TT; p.ldc = TT;
        p.bias = ybias; p.bias_bstride = 240; p.scale = 1.f; p.store_ncols = 240;
        gemm_kernel<2><<<dim3(16, 2, 16), 256, 0, stream>>>(p);
    }
}

// Round 4
// 1951.938 us; speedup vs baseline: 1.4486x; 1.0525x over previous
//
#include <hip/hip_runtime.h>
#include <cstdint>
#include <cstddef>

typedef unsigned short u16;
typedef __attribute__((ext_vector_type(8))) short short8;
typedef __attribute__((ext_vector_type(4))) float f32x4;

static constexpr int BB = 16, DIN = 240, NN = 2048, TT = 2048;
static constexpr long long Y_SIZE = (long long)BB * DIN * TT;          // 7,864,320 f32
static constexpr float SQRT_HALF_F = 0.70710678118654752440f;
static constexpr int HPAD = 64;                 // zero-pad rows each side of h (max shift 54)
static constexpr int HROWS = NN + 2 * HPAD;     // 2176

#define DEVI __device__ __forceinline__

DEVI u16 f2bf(float f) {
    unsigned u = __builtin_bit_cast(unsigned, f);
    u += 0x7FFFu + ((u >> 16) & 1u);
    return (u16)(u >> 16);
}
DEVI float bf2f(u16 h) {
    unsigned u = ((unsigned)h) << 16;
    return __builtin_bit_cast(float, u);
}

DEVI void gld16(const void* g, const void* l) {
    __builtin_amdgcn_global_load_lds(
        (const __attribute__((address_space(1))) unsigned int*)g,
        (__attribute__((address_space(3))) unsigned int*)l, 16, 0, 0);
}

// GLU column permutation for the 256-wide tile geometry: GEMM col g -> conv output
// channel. Within each wave's 64-col span, fragments n={0,2} are "a" channels and
// n={1,3} the matching gate "b" channels at +16 GEMM cols.
DEVI int glu_perm(int g) {
    int tile = g >> 8, r = g & 255;
    int wcq = r >> 6, r2 = r & 63;
    int n = r2 >> 4, fr = r2 & 15;
    return tile * 128 + wcq * 32 + (n >> 1) * 16 + fr + (n & 1) * 512;
}

// ---------------- GEMM params ----------------
// C[row][col] = scale * sum_taps sum_k A[row+shift][k] * B[col][k]  (+bias)
struct GemmP {
    const u16* A; long long a_bstride; int lda;
    const u16* Bw; long long b_bstride; long long b_tapstride; int ldb;
    int ntaps; int shift0; int dshift; int Kt; int ks_log2;
    void* out; long long o_bstride; int ldc;
    const float* bias; int bias_bstride;
    float scale;
    int store_ncols;
};

#define FENCE() asm volatile("" ::: "memory")
#define SBAR()  do { FENCE(); __builtin_amdgcn_s_barrier(); FENCE(); } while (0)

// =============== 256x256 8-phase MFMA GEMM (BK=64, 8 waves, counted vmcnt) ===============
// OUTK: 1 = bf16 row-major col-bias (+scale). 4 = GLU fused epilogue. 5 = bf16 row-bias.
template <int OUTK>
__global__ __launch_bounds__(512, 2)
void gemm256(GemmP p, int tilesM, int tilesN) {
    __shared__ __align__(16) u16 As[2][256 * 64];
    __shared__ __align__(16) u16 Bs[2][256 * 64];
    const int tid = threadIdx.x;
    const int lane = tid & 63;
    const int wv = tid >> 6;
    const int wr = wv >> 2, wcq = wv & 3;          // 2M x 4N wave grid
    const int fr = lane & 15, fq = lane >> 4;

    // bijective XCD-aware block swizzle (grid always a multiple of 8)
    const int nwg = gridDim.x;
    int widx = (blockIdx.x & 7) * (nwg >> 3) + (blockIdx.x >> 3);
    const int mt = widx % tilesM; widx /= tilesM;
    const int nt = widx % tilesN;
    const int bz = widx / tilesN;
    const int n0 = mt * 256, c0 = nt * 256;

    const u16* Abase = p.A + (long long)bz * p.a_bstride;
    const u16* Bbase = p.Bw + (long long)bz * p.b_bstride;
    const int kmask = (1 << p.ks_log2) - 1;
    const int tot = p.ntaps << p.ks_log2;

    f32x4 acc[8][4];
#pragma unroll
    for (int m = 0; m < 8; ++m)
#pragma unroll
        for (int n = 0; n < 4; ++n) acc[m][n] = (f32x4){0.f, 0.f, 0.f, 0.f};

    // ---- staging: one half-tile (128 rows x 64 cols u16) per call; 2 gld/wave.
    // LDS linear; swizzle realized by pre-permuting the GLOBAL source column slot.
    const int srow = (lane >> 3);            // row within 8-row stripe
    const int sslot = lane & 7;              // 16B slot 0..7

    auto STAGE_A = [&](int t, int half) {
        if (t >= tot) return;
        const int buf = t & 1;
        const int tap = t >> p.ks_log2;
        const int ks = (t & kmask) << 6;
        const u16* a = Abase +
            (long long)(n0 + p.shift0 + tap * p.dshift + half * 128) * p.lda + ks;
        u16* dst = &As[buf][(half * 128 + wv * 16) * 64];
#pragma unroll
        for (int i = 0; i < 2; ++i) {
            int rg = wv * 16 + i * 8 + srow;
            int js = (sslot ^ (rg & 7)) << 3;
            gld16(a + (long long)rg * p.lda + js, dst + i * 512);
        }
    };
    auto STAGE_B = [&](int t, int half) {
        if (t >= tot) return;
        const int buf = t & 1;
        const int tap = t >> p.ks_log2;
        const int ks = (t & kmask) << 6;
        const u16* b = Bbase + (long long)tap * p.b_tapstride +
            (long long)(c0 + half * 128) * p.ldb + ks;
        u16* dst = &Bs[buf][(half * 128 + wv * 16) * 64];
#pragma unroll
        for (int i = 0; i < 2; ++i) {
            int rg = wv * 16 + i * 8 + srow;
            int js = (sslot ^ (rg & 7)) << 3;
            gld16(b + (long long)rg * p.ldb + js, dst + i * 512);
        }
    };

    // ---- prologue: tile0 complete + tile1 B halves; counted drain ----
    STAGE_A(0, 0); STAGE_A(0, 1); STAGE_B(0, 0); STAGE_B(0, 1);
    STAGE_B(1, 0); STAGE_B(1, 1);
    asm volatile("s_waitcnt vmcnt(4)" ::: "memory");
    __builtin_amdgcn_s_barrier();
    FENCE();

    short8 af[4][2], bf0[2][2], bf1[2][2];

#define READ_AQ(MQ)                                                            \
    _Pragma("unroll")                                                          \
    for (int mi = 0; mi < 4; ++mi) {                                           \
        _Pragma("unroll")                                                      \
        for (int kk = 0; kk < 2; ++kk) {                                       \
            int row = wr * 128 + (MQ) * 64 + mi * 16 + fr;                     \
            int slot = (kk * 4 + fq) ^ (row & 7);                              \
            af[mi][kk] = *(const short8*)&Ab[row * 64 + slot * 8];             \
        }                                                                      \
    }
#define READ_BQ(BF, NQ)                                                        \
    _Pragma("unroll")                                                          \
    for (int ni = 0; ni < 2; ++ni) {                                           \
        _Pragma("unroll")                                                      \
        for (int kk = 0; kk < 2; ++kk) {                                       \
            int col = wcq * 64 + (NQ) * 32 + ni * 16 + fr;                     \
            int slot = (kk * 4 + fq) ^ (col & 7);                              \
            BF[ni][kk] = *(const short8*)&Bb[col * 64 + slot * 8];             \
        }                                                                      \
    }
#define MFMA_Q(MQ, NQ, BF)                                                     \
    __builtin_amdgcn_s_setprio(1);                                            \
    _Pragma("unroll")                                                          \
    for (int mi = 0; mi < 4; ++mi) {                                           \
        _Pragma("unroll")                                                      \
        for (int ni = 0; ni < 2; ++ni) {                                       \
            _Pragma("unroll")                                                  \
            for (int kk = 0; kk < 2; ++kk)                                     \
                acc[(MQ) * 4 + mi][(NQ) * 2 + ni] =                            \
                    __builtin_amdgcn_mfma_f32_16x16x32_bf16(                   \
                        af[mi][kk], BF[ni][kk],                                \
                        acc[(MQ) * 4 + mi][(NQ) * 2 + ni], 0, 0, 0);           \
        }                                                                      \
    }                                                                          \
    __builtin_amdgcn_s_setprio(0)

    for (int t = 0; t < tot; ++t) {
        const u16* Ab = As[t & 1];
        const u16* Bb = Bs[t & 1];
        // phase 1: quadrant m0 x n0; stage (t+1).A0 (other buffer)
        READ_AQ(0);
        READ_BQ(bf0, 0);
        STAGE_A(t + 1, 0);
        SBAR();
        MFMA_Q(0, 0, bf0);
        SBAR();
        // phase 2: quadrant m0 x n1; stage (t+1).A1
        READ_BQ(bf1, 1);
        STAGE_A(t + 1, 1);
        SBAR();
        MFMA_Q(0, 1, bf1);
        SBAR();
        // phase 3: quadrant m1 x n1; stage (t+2).B0 (this buffer — B reads done @ph2)
        READ_AQ(1);
        STAGE_B(t + 2, 0);
        SBAR();
        MFMA_Q(1, 1, bf1);
        SBAR();
        // phase 4: quadrant m1 x n0 (regs only); stage (t+2).B1; counted drain
        STAGE_B(t + 2, 1);
        SBAR();
        MFMA_Q(1, 0, bf0);
        asm volatile("s_waitcnt vmcnt(4)" ::: "memory");
        SBAR();
    }
#undef READ_AQ
#undef READ_BQ
#undef MFMA_Q

    if constexpr (OUTK == 4) {
        // GLU: a,b pairs in adjacent 16-col fragments; residual h_in via A operand.
        const float* bp = p.bias;
#pragma unroll
        for (int m = 0; m < 8; ++m) {
#pragma unroll
            for (int pr = 0; pr < 2; ++pr) {
                int ca = c0 + wcq * 64 + (2 * pr) * 16 + fr;
                int chan = (c0 >> 1) + wcq * 32 + pr * 16 + fr;
                float biasa = bp[ca], biasb = bp[ca + 16];
#pragma unroll
                for (int r = 0; r < 4; ++r) {
                    int row = n0 + wr * 128 + m * 16 + fq * 4 + r;
                    float a = acc[m][2 * pr][r] + biasa;
                    float bq = acc[m][2 * pr + 1][r] + biasb;
                    float sig = 1.f / (1.f + __expf(-bq));
                    float h = bf2f(Abase[(long long)row * p.lda + chan]);
                    ((u16*)p.out)[(long long)bz * p.o_bstride + (long long)row * p.ldc + chan]
                        = f2bf((h + a * sig) * SQRT_HALF_F);
                }
            }
        }
        return;
    } else {
        const float* bias = p.bias ? p.bias + (long long)bz * p.bias_bstride : nullptr;
#pragma unroll
        for (int m = 0; m < 8; ++m) {
#pragma unroll
            for (int n = 0; n < 4; ++n) {
                int col = c0 + wcq * 64 + n * 16 + fr;
                float cb = (OUTK == 1 && bias) ? bias[col] : 0.f;
#pragma unroll
                for (int r = 0; r < 4; ++r) {
                    int row = n0 + wr * 128 + m * 16 + fq * 4 + r;
                    float v = acc[m][n][r] * p.scale + cb;
                    if (OUTK == 5) v += bias[row];
                    ((u16*)p.out)[(long long)bz * p.o_bstride + (long long)row * p.ldc + col]
                        = f2bf(v);
                }
            }
        }
    }
}

// =============== 128x128 GEMM (kept for the N=240 transposed-f32 post GEMM) ===============
template <int OUTK>
__global__ __launch_bounds__(256, 2)
void gemm_kernel(GemmP p) {
    __shared__ u16 As[128 * 64];
    __shared__ u16 Bs[128 * 64];
    const int tid = threadIdx.x;
    const int lane = tid & 63, wv = tid >> 6;
    const int wr = wv >> 1, wc = wv & 1;
    const int bz = blockIdx.z;
    const int n0 = blockIdx.x * 128;
    const int c0 = blockIdx.y * 128;
    const u16* Abase = p.A + (long long)bz * p.a_bstride;
    const u16* Bbase = p.Bw + (long long)bz * p.b_bstride;

    f32x4 acc[4][4];
#pragma unroll
    for (int i = 0; i < 4; ++i)
#pragma unroll
        for (int j = 0; j < 4; ++j) acc[i][j] = (f32x4){0.f, 0.f, 0.f, 0.f};

    const int ksteps = p.Kt >> 6;
    const int tot = p.ntaps * ksteps;
    const int srow = lane >> 3;
    const int scol = (lane & 7) * 8;
    const int fr = lane & 15;
    const int fk = (lane >> 4) * 8;

    for (int t = 0; t < tot; ++t) {
        const int tap = t / ksteps;
        const int ks = (t - tap * ksteps) << 6;
        const int shift = p.shift0 + tap * p.dshift;
        __syncthreads();
        {
            const u16* asrc = Abase + (long long)(n0 + shift) * p.lda + ks;
#pragma unroll
            for (int c = 0; c < 4; ++c) {
                int chunk = wv * 4 + c;
                int row = chunk * 8 + srow;
                gld16(asrc + (long long)row * p.lda + scol, &As[chunk * 512]);
            }
            const u16* bsrc = Bbase + (long long)tap * p.b_tapstride + (long long)c0 * p.ldb + ks;
#pragma unroll
            for (int c = 0; c < 4; ++c) {
                int chunk = wv * 4 + c;
                int row = chunk * 8 + srow;
                gld16(bsrc + (long long)row * p.ldb + scol, &Bs[chunk * 512]);
            }
        }
        asm volatile("s_waitcnt vmcnt(0)" ::: "memory");
        __syncthreads();
#pragma unroll
        for (int kk = 0; kk < 2; ++kk) {
            short8 af[4], bfr[4];
#pragma unroll
            for (int m = 0; m < 4; ++m) {
                int arow = wr * 64 + m * 16 + fr;
                af[m] = *(const short8*)&As[arow * 64 + kk * 32 + fk];
            }
#pragma unroll
            for (int nn2 = 0; nn2 < 4; ++nn2) {
                int brow = wc * 64 + nn2 * 16 + fr;
                bfr[nn2] = *(const short8*)&Bs[brow * 64 + kk * 32 + fk];
            }
#pragma unroll
            for (int m = 0; m < 4; ++m)
#pragma unroll
                for (int nn2 = 0; nn2 < 4; ++nn2)
                    acc[m][nn2] = __builtin_amdgcn_mfma_f32_16x16x32_bf16(
                        af[m], bfr[nn2], acc[m][nn2], 0, 0, 0);
        }
    }

    const float* bias = p.bias ? p.bias + (long long)bz * p.bias_bstride : nullptr;
#pragma unroll
    for (int m = 0; m < 4; ++m) {
#pragma unroll
        for (int nn2 = 0; nn2 < 4; ++nn2) {
#pragma unroll
            for (int r = 0; r < 4; ++r) {
                int row = n0 + wr * 64 + m * 16 + ((lane >> 4) << 2) + r;
                int col = c0 + wc * 64 + nn2 * 16 + (lane & 15);
                if (col >= p.store_ncols) continue;
                float v = acc[m][nn2][r] * p.scale;
                if (bias) v += bias[col];
                long long off = (OUTK == 0 || OUTK == 1)
                                    ? (long long)row * p.ldc + col
                                    : (long long)col * p.ldc + row;
                long long idx = (long long)bz * p.o_bstride + off;
                if (OUTK == 0 || OUTK == 2) ((float*)p.out)[idx] = v;
                else ((u16*)p.out)[idx] = f2bf(v);
            }
        }
    }
}

// ---------------- elementwise / helper kernels ----------------

__global__ void cvt_glu(const float* src, u16* dst) {
    long long t = (long long)blockIdx.x * blockDim.x + threadIdx.x;
    const long long total = 8LL * 5 * 1024 * 512;
    if (t >= total) return;
    int i = (int)(t % 512); long long r = t / 512;
    int g = (int)(r % 1024); r /= 1024;
    int k = (int)(r % 5); int l = (int)(r / 5);
    int o = glu_perm(g);
    dst[t] = f2bf(src[(((long long)l * 1024 + o) * 512 + i) * 5 + k]);
}

__global__ void perm_bias(const float* gb, float* biasP) {
    int t = blockIdx.x * 256 + threadIdx.x;
    if (t >= 8 * 1024) return;
    int g = t & 1023, l = t >> 10;
    biasP[t] = gb[l * 1024 + glu_perm(g)];
}

__global__ void cvt_pad(const float* src, u16* dst, int Os, int Is, int Od, int Id) {
    long long t = (long long)blockIdx.x * blockDim.x + threadIdx.x;
    if (t >= (long long)Od * Id) return;
    int i = (int)(t % Id); int o = (int)(t / Id);
    float v = (o < Os && i < Is) ? src[(long long)o * Is + i] : 0.f;
    dst[t] = f2bf(v);
}

// src [b][Csrc][Len] f32 -> dst [b][Len][Cdst] bf16 (zero-pad channels)
__global__ void transpose_in(const float* src, u16* dst, int Csrc, int Cdst, int Len) {
    __shared__ float tile[32][33];
    int b = blockIdx.z;
    int n0 = blockIdx.x * 32, c0 = blockIdx.y * 32;
    int tx = threadIdx.x, ty = threadIdx.y;
    int c = c0 + ty, n = n0 + tx;
    float v = 0.f;
    if (c < Csrc) v = src[((long long)b * Csrc + c) * Len + n];
    tile[ty][tx] = v;
    __syncthreads();
    dst[((long long)b * Len + (n0 + ty)) * Cdst + (c0 + tx)] = f2bf(tile[tx][ty]);
}

__global__ void zero_pads(u16* h) {
    long long t = (long long)blockIdx.x * blockDim.x + threadIdx.x;
    const long long total = (long long)BB * 128 * 512;
    if (t >= total) return;
    int c = (int)(t % 512); long long r = t / 512;
    int rr = (int)(r % 128); int b = (int)(r / 128);
    int row = rr < HPAD ? rr : (HROWS - 128 + rr);
    h[((long long)b * HROWS + row) * 512 + c] = 0;
}

__global__ void prebias_kernel(const float* ct, const float* wcpre, const float* wpre,
                               const float* bpre, float* qbias) {
    __shared__ float s[240];
    int b = blockIdx.x; int tid = threadIdx.x;
    if (tid < 240) {
        float a = 0.f;
        for (int c = 0; c < 8; ++c) a += ct[b * 8 + c] * wcpre[c * 240 + tid];
        s[tid] = a;
    }
    __syncthreads();
    for (int o = tid; o < 512; o += 256) {
        float a = bpre[o];
        for (int d0 = 0; d0 < 240; ++d0) a += wpre[o * 240 + d0] * s[d0];
        qbias[b * 512 + o] = a;
    }
}

__global__ void postbias_kernel(const float* ct, const float* wcpost, const float* wpost,
                                const float* bpost, float* ybias) {
    __shared__ float s[1024];
    int b = blockIdx.x; int tid = threadIdx.x;
    for (int e = tid; e < 1024; e += 256) {
        float a = 0.f;
        for (int c = 0; c < 8; ++c) a += ct[b * 8 + c] * wcpost[c * 1024 + e];
        s[e] = a;
    }
    __syncthreads();
    if (tid < 240) {
        float a = bpost[tid];
        for (int e = 0; e < 1024; ++e) a += wpost[tid * 1024 + e] * s[e];
        ybias[b * 240 + tid] = a;
    }
}

// One wave per (b,t): read bf16 score row, softmax, write normalized bf16 AT row.
__global__ __launch_bounds__(256)
void softmax_rows(const u16* St, u16* AT) {
    int b = blockIdx.y;
    int t = blockIdx.x * 4 + (threadIdx.x >> 6);
    int lane = threadIdx.x & 63;
    const u16* row = St + ((long long)b * TT + t) * NN;
    short8 v[4];
#pragma unroll
    for (int i = 0; i < 4; ++i) v[i] = ((const short8*)row)[i * 64 + lane];
    float f[32];
#pragma unroll
    for (int i = 0; i < 4; ++i)
#pragma unroll
        for (int j = 0; j < 8; ++j) f[i * 8 + j] = bf2f((u16)v[i][j]);
    float m = -3.4e38f;
#pragma unroll
    for (int i = 0; i < 32; ++i) m = fmaxf(m, f[i]);
#pragma unroll
    for (int s = 1; s < 64; s <<= 1) m = fmaxf(m, __shfl_xor(m, s, 64));
    float sum = 0.f;
#pragma unroll
    for (int i = 0; i < 32; ++i) { f[i] = __expf(f[i] - m); sum += f[i]; }
#pragma unroll
    for (int s = 1; s < 64; s <<= 1) sum += __shfl_xor(sum, s, 64);
    float li = 1.f / sum;
    u16* atrow = AT + ((long long)b * TT + t) * NN;
#pragma unroll
    for (int i = 0; i < 4; ++i) {
        short8 pk;
#pragma unroll
        for (int j = 0; j < 8; ++j) pk[j] = (short)f2bf(f[i * 8 + j] * li);
        ((short8*)atrow)[i * 64 + lane] = pk;
    }
}

// AT bf16 [b][t][n] -> A f32 [b][n][t] (final output region)
__global__ void transpose_out(const u16* AT, float* A) {
    __shared__ float tile[32][33];
    int b = blockIdx.z;
    int n0 = blockIdx.x * 32, t0 = blockIdx.y * 32;
    int tx = threadIdx.x, ty = threadIdx.y;
#pragma unroll
    for (int k = 0; k < 4; ++k) {
        int t = t0 + ty + k * 8;
        tile[ty + k * 8][tx] = bf2f(AT[((long long)b * TT + t) * NN + n0 + tx]);
    }
    __syncthreads();
#pragma unroll
    for (int k = 0; k < 4; ++k) {
        int n = n0 + ty + k * 8;
        A[((long long)b * NN + n) * TT + t0 + tx] = tile[tx][ty + k * 8];
    }
}

// ---------------- host orchestration ----------------

extern "C" void kernel_launch(void* const* d_in, const int* in_sizes, int n_in,
                              void* d_out, int out_size, void* d_ws, size_t ws_size,
                              hipStream_t stream) {
    const float* in_s        = (const float*)d_in[0];
    const float* in_t        = (const float*)d_in[1];
    const float* c_t         = (const float*)d_in[2];
    const float* enc_start_w = (const float*)d_in[3];
    const float* enc_start_b = (const float*)d_in[4];
    const float* glu_w       = (const float*)d_in[5];
    const float* glu_b       = (const float*)d_in[6];
    const float* enc_end_w   = (const float*)d_in[7];
    const float* enc_end_b   = (const float*)d_in[8];
    const float* wc_pre      = (const float*)d_in[9];
    const float* w_pre       = (const float*)d_in[10];
    const float* b_pre       = (const float*)d_in[11];
    const float* wc_post     = (const float*)d_in[12];
    const float* w_post      = (const float*)d_in[13];
    const float* b_post      = (const float*)d_in[14];

    // workspace layout
    char* w = (char*)d_ws;
    u16* wglu   = (u16*)w; w += 8LL * 5 * 1024 * 512 * 2;
    u16* wstart = (u16*)w; w += 512LL * 256 * 2;
    u16* wend   = (u16*)w; w += 1024LL * 512 * 2;
    u16* wpre   = (u16*)w; w += 512LL * 256 * 2;
    u16* wpost  = (u16*)w; w += 256LL * 1024 * 2;
    u16* XS     = (u16*)w; w += (long long)BB * NN * 256 * 2;
    u16* XT     = (u16*)w; w += (long long)BB * TT * 256 * 2;
    u16* h0     = (u16*)w; w += (long long)BB * HROWS * 512 * 2;
    u16* h1     = (u16*)w; w += (long long)BB * HROWS * 512 * 2;
    u16* Kb     = (u16*)w; w += (long long)BB * NN * 512 * 2;
    u16* Vb     = (u16*)w; w += (long long)BB * 512 * NN * 2;
    u16* Rc     = (u16*)w; w += (long long)BB * TT * 1024 * 2;
    u16* ATb    = (u16*)w; w += (long long)BB * TT * NN * 2;
    float* qbias = (float*)w; w += 16LL * 512 * 4;
    float* ybias = (float*)w; w += 16LL * 256 * 4;
    float* biasP = (float*)w; w += 8LL * 1024 * 4;
    if ((size_t)(w - (char*)d_ws) > ws_size) return;  // insufficient scratch — bail

    float* yout = (float*)d_out;
    float* Areg = yout + Y_SIZE;       // final A f32 [b][n][t]
    u16* Sbf = (u16*)Areg;             // transient bf16 scores [b][t][n]

    // ---- conversions / setup ----
    cvt_glu<<<(8LL * 5 * 1024 * 512 + 255) / 256, 256, 0, stream>>>(glu_w, wglu);
    perm_bias<<<(8 * 1024 + 255) / 256, 256, 0, stream>>>(glu_b, biasP);
    cvt_pad<<<(512 * 256 + 255) / 256, 256, 0, stream>>>(enc_start_w, wstart, 512, 240, 512, 256);
    cvt_pad<<<(1024 * 512 + 255) / 256, 256, 0, stream>>>(enc_end_w, wend, 1024, 512, 1024, 512);
    cvt_pad<<<(512 * 256 + 255) / 256, 256, 0, stream>>>(w_pre, wpre, 512, 240, 512, 256);
    cvt_pad<<<(256 * 1024 + 255) / 256, 256, 0, stream>>>(w_post, wpost, 240, 1024, 256, 1024);
    transpose_in<<<dim3(NN / 32, 256 / 32, BB), dim3(32, 32), 0, stream>>>(in_s, XS, 240, 256, NN);
    transpose_in<<<dim3(TT / 32, 256 / 32, BB), dim3(32, 32), 0, stream>>>(in_t, XT, 240, 256, TT);
    zero_pads<<<((long long)BB * 128 * 512 + 255) / 256, 256, 0, stream>>>(h0);
    zero_pads<<<((long long)BB * 128 * 512 + 255) / 256, 256, 0, stream>>>(h1);
    prebias_kernel<<<16, 256, 0, stream>>>(c_t, wc_pre, w_pre, b_pre, qbias);
    postbias_kernel<<<16, 256, 0, stream>>>(c_t, wc_post, w_post, b_post, ybias);

    // ---- enc_start: XS[2048][256] x wstart[512][256] -> h0 bf16 [n][512] ----
    {
        GemmP p{}; p.A = XS; p.a_bstride = (long long)NN * 256; p.lda = 256;
        p.Bw = wstart; p.b_bstride = 0; p.b_tapstride = 0; p.ldb = 256;
        p.ntaps = 1; p.shift0 = 0; p.dshift = 0; p.Kt = 256; p.ks_log2 = 2;
        p.out = h0 + HPAD * 512; p.o_bstride = (long long)HROWS * 512; p.ldc = 512;
        p.bias = enc_start_b; p.bias_bstride = 0; p.scale = 1.f; p.store_ncols = 512;
        gemm256<1><<<8 * 2 * 16, 512, 0, stream>>>(p, 8, 2);
    }

    // ---- 8 GLU blocks (fused epilogue) ----
    const int dils[8] = {1, 3, 9, 27, 1, 3, 9, 27};
    u16* hin = h0; u16* hout = h1;
    for (int l = 0; l < 8; ++l) {
        GemmP q{}; q.A = hin + HPAD * 512; q.a_bstride = (long long)HROWS * 512; q.lda = 512;
        q.Bw = wglu + (long long)l * 5 * 1024 * 512; q.b_bstride = 0;
        q.b_tapstride = 1024LL * 512; q.ldb = 512;
        q.ntaps = 5; q.shift0 = -2 * dils[l]; q.dshift = dils[l]; q.Kt = 512; q.ks_log2 = 3;
        q.out = hout + HPAD * 512; q.o_bstride = (long long)HROWS * 512; q.ldc = 512;
        q.bias = biasP + l * 1024; q.bias_bstride = 0; q.scale = 1.f; q.store_ncols = 1024;
        gemm256<4><<<8 * 4 * 16, 512, 0, stream>>>(q, 8, 4);
        u16* tmp = hin; hin = hout; hout = tmp;
    }

    // ---- enc_end K: h[n][512] x wend_K[512][512] -> Kb bf16 [n][512] ----
    {
        GemmP p{}; p.A = hin + HPAD * 512; p.a_bstride = (long long)HROWS * 512; p.lda = 512;
        p.Bw = wend; p.b_bstride = 0; p.b_tapstride = 0; p.ldb = 512;
        p.ntaps = 1; p.shift0 = 0; p.dshift = 0; p.Kt = 512; p.ks_log2 = 3;
        p.out = Kb; p.o_bstride = (long long)NN * 512; p.ldc = 512;
        p.bias = enc_end_b; p.bias_bstride = 0; p.scale = 1.f; p.store_ncols = 512;
        gemm256<1><<<8 * 2 * 16, 512, 0, stream>>>(p, 8, 2);
    }
    // ---- enc_end V (operand-swapped): Vb[d][n] = wend_V[d][k] · h[n][k], row-bias ----
    {
        GemmP p{}; p.A = wend + 512LL * 512; p.a_bstride = 0; p.lda = 512;
        p.Bw = hin + HPAD * 512; p.b_bstride = (long long)HROWS * 512; p.b_tapstride = 0; p.ldb = 512;
        p.ntaps = 1; p.shift0 = 0; p.dshift = 0; p.Kt = 512; p.ks_log2 = 3;
        p.out = Vb; p.o_bstride = 512LL * NN; p.ldc = NN;
        p.bias = enc_end_b + 512; p.bias_bstride = 0; p.scale = 1.f; p.store_ncols = NN;
        gemm256<5><<<2 * 8 * 16, 512, 0, stream>>>(p, 2, 8);
    }

    // ---- pre-decoder: Q into Rc columns 512..1023 ----
    {
        GemmP p{}; p.A = XT; p.a_bstride = (long long)TT * 256; p.lda = 256;
        p.Bw = wpre; p.b_bstride = 0; p.b_tapstride = 0; p.ldb = 256;
        p.ntaps = 1; p.shift0 = 0; p.dshift = 0; p.Kt = 256; p.ks_log2 = 2;
        p.out = Rc + 512; p.o_bstride = (long long)TT * 1024; p.ldc = 1024;
        p.bias = qbias; p.bias_bstride = 512; p.scale = 1.f; p.store_ncols = 512;
        gemm256<1><<<8 * 2 * 16, 512, 0, stream>>>(p, 8, 2);
    }

    // ---- scores: St[t][n] = Q[t]·K[n] / sqrt(d), bf16 into Sbf ----
    {
        GemmP p{}; p.A = Rc + 512; p.a_bstride = (long long)TT * 1024; p.lda = 1024;
        p.Bw = Kb; p.b_bstride = (long long)NN * 512; p.b_tapstride = 0; p.ldb = 512;
        p.ntaps = 1; p.shift0 = 0; p.dshift = 0; p.Kt = 512; p.ks_log2 = 3;
        p.out = Sbf; p.o_bstride = (long long)TT * NN; p.ldc = NN;
        p.bias = nullptr; p.bias_bstride = 0; p.scale = 0.04419417382415922f; // 1/sqrt(512)
        p.store_ncols = NN;
        gemm256<1><<<8 * 8 * 16, 512, 0, stream>>>(p, 8, 8);
    }

    // ---- softmax over n (contiguous), normalized AT bf16 ----
    softmax_rows<<<dim3(TT / 4, BB), 256, 0, stream>>>(Sbf, ATb);
    // ---- AT -> final A f32 [n][t] (overwrites dead Sbf region) ----
    transpose_out<<<dim3(NN / 32, TT / 32, BB), dim3(32, 8), 0, stream>>>(ATb, Areg);

    // ---- R = V x A  (C[t][d] = sum_n AT[t][n] * V[d][n]) into Rc cols 0..511 ----
    {
        GemmP p{}; p.A = ATb; p.a_bstride = (long long)TT * NN; p.lda = NN;
        p.Bw = Vb; p.b_bstride = 512LL * NN; p.b_tapstride = 0; p.ldb = NN;
        p.ntaps = 1; p.shift0 = 0; p.dshift = 0; p.Kt = NN; p.ks_log2 = 5;
        p.out = Rc; p.o_bstride = (long long)TT * 1024; p.ldc = 1024;
        p.bias = nullptr; p.bias_bstride = 0; p.scale = 1.f; p.store_ncols = 512;
        gemm256<1><<<8 * 2 * 16, 512, 0, stream>>>(p, 8, 2);
    }

    // ---- post-decoder: Rc[t][1024] x wpost -> y f32 [b][240][t] (transposed store) ----
    {
        GemmP p{}; p.A = Rc; p.a_bstride = (long long)TT * 1024; p.lda = 1024;
        p.Bw = wpost; p.b_bstride = 0; p.b_tapstride = 0; p.ldb = 1024;
        p.ntaps = 1; p.shift0 = 0; p.dshift = 0; p.Kt = 1024; p.ks_log2 = 4;
        p.out = yout; p.o_bstride = (long long)DIN * TT; p.ldc = TT;
        p.bias = ybias; p.bias_bstride = 240; p.scale = 1.f; p.store_ncols = 240;
        gemm_kernel<2><<<dim3(16, 2, 16), 256, 0, stream>>>(p);
    }
}